// Round 13
// baseline (201.597 us; speedup 1.0000x reference)
//
#include <hip/hip_runtime.h>
#include <cstdint>
#include <cstddef>

// ---------------- problem constants ----------------
#define BATCH 16
#define NBOX 25200
#define NCH 85          // 4 box + 1 obj + 80 cls
#define KPRE 1024
#define MAXDET 1000
#define NCAND_MAX 4096
#define HS 65536        // histogram buckets (key >> 16)
#define SHIFT 16
#define IDX_PAD 0xFFFFFFFFu

__device__ __forceinline__ unsigned key_of(float s) {
    // monotone map: larger score -> SMALLER key (ascending sort = descending score)
    unsigned u = __float_as_uint(s);
    unsigned m = (u & 0x80000000u) ? ~u : (u | 0x80000000u);
    return ~m;
}

// ---------------- kernel 0: fast workspace zero ----------------
__global__ __launch_bounds__(256) void zero_kernel(uint4* __restrict__ p, int n16) {
    int i = blockIdx.x * 256 + threadIdx.x;
    if (i < n16) p[i] = make_uint4(0u, 0u, 0u, 0u);
}

// ---------------- kernel 1: per-box max score, 4 lanes/box lane-contiguous chunks ----------------
// Lane q of a box loads float4 chunks q,q+4,..,q+16: the 4 lanes' 16B are contiguous 64B
// -> ~1 L1 line per box per instruction (vs 22/box for the 2-lane layout).
__global__ __launch_bounds__(256, 2) void score_kernel(const float* __restrict__ x,
                                                       unsigned* __restrict__ k32,
                                                       unsigned* __restrict__ hist) {
    int gid = blockIdx.x * 256 + threadIdx.x;
    int box = gid >> 2;
    int q = gid & 3;
    size_t base = (size_t)box * NCH;
    const float* rowp = x + base;

    float obj = rowp[4];                              // 4-lane broadcast (1 line)
    float4 r0 = ((const float4*)rowp)[q];             // chunk q     (floats 4q..4q+3)
    float4 r1 = ((const float4*)rowp)[q + 4];
    float4 r2 = ((const float4*)rowp)[q + 8];
    float4 r3 = ((const float4*)rowp)[q + 12];
    float4 r4 = ((const float4*)rowp)[q + 16];
    float4 rt = ((const float4*)rowp)[20];            // floats 80..83 (cls 75..78), broadcast
    float c79 = rowp[84];                             // cls 79, broadcast

    // mask non-class floats in chunk j=0: q==0 -> floats 0..3 (all box), q==1 -> float 4 (obj)
    if (q == 0) { r0.x = -1e30f; r0.y = -1e30f; r0.z = -1e30f; r0.w = -1e30f; }
    if (q == 1) { r0.x = -1e30f; }

    float v = fmaxf(fmaxf(r0.x, r0.y), fmaxf(r0.z, r0.w));
    v = fmaxf(v, fmaxf(fmaxf(r1.x, r1.y), fmaxf(r1.z, r1.w)));
    v = fmaxf(v, fmaxf(fmaxf(r2.x, r2.y), fmaxf(r2.z, r2.w)));
    v = fmaxf(v, fmaxf(fmaxf(r3.x, r3.y), fmaxf(r3.z, r3.w)));
    v = fmaxf(v, fmaxf(fmaxf(r4.x, r4.y), fmaxf(r4.z, r4.w)));
    v = fmaxf(v, fmaxf(fmaxf(rt.x, rt.y), fmaxf(rt.z, rt.w)));
    v = fmaxf(v, c79);
    v = fmaxf(v, __shfl_xor(v, 1));
    v = fmaxf(v, __shfl_xor(v, 2));                   // max(cls) across 4 lanes

    if (q == 0) {
        float conf = obj * v;                         // = max(cls*obj) exactly (monotone FP mul)
        bool validb = (obj > 0.25f) && (conf > 0.25f);
        float score = validb ? conf : -1.0f;
        unsigned k = key_of(score);
        k32[box] = k;
        if (validb) {
            int b = box / NBOX;
            atomicAdd(&hist[b * HS + (int)(k >> SHIFT)], 1u);  // commutative -> deterministic
        }
    }
}

// ---------------- kernel 2: fused per-batch front tail v2 (1 block / batch, ~7 barriers) ----------------
// cutoff -> 4-barrier deterministic compaction -> RANK-BY-COUNT (no sort) -> argmax+box.
__global__ __launch_bounds__(1024) void mega_front(const float* __restrict__ x,
                                                   const unsigned* __restrict__ k32,
                                                   const unsigned* __restrict__ hist,
                                                   float* __restrict__ topconf,
                                                   float4* __restrict__ topbox,
                                                   float4* __restrict__ topoff,
                                                   float* __restrict__ topcls) {
#pragma clang fp contract(off)
    __shared__ unsigned long long keys[NCAND_MAX];   // 32 KB
    __shared__ unsigned part[1024];
    __shared__ unsigned wsum[16];
    __shared__ unsigned cnt[25][16];
    __shared__ unsigned waveOff[25][16];
    __shared__ unsigned chunkBase[25];
    __shared__ unsigned totc[25];
    __shared__ unsigned cutP, nTot;
    int b = blockIdx.x, t = threadIdx.x;
    int lane = t & 63, wv = t >> 6;

    // ---- phase A: histogram cutoff covering rank KPRE (2 barriers) ----
    const unsigned* h = hist + (size_t)b * HS;
    {
        const uint4* h4 = (const uint4*)(h + t * 64);
        unsigned s = 0;
        #pragma unroll
        for (int j = 0; j < 16; j++) { uint4 v4 = h4[j]; s += v4.x + v4.y + v4.z + v4.w; }
        part[t] = s;
        unsigned ws = s;
        #pragma unroll
        for (int off = 1; off < 64; off <<= 1) ws += __shfl_xor(ws, off);
        if (lane == 0) wsum[wv] = ws;
    }
    __syncthreads();
    if (t == 0) {
        unsigned cum = 0; int W = -1;
        for (int w = 0; w < 16; w++)
            if (W < 0) { if (cum + wsum[w] >= KPRE) W = w; else cum += wsum[w]; }
        int T = -1;
        if (W >= 0)
            for (int i = 0; i < 64; i++)
                if (T < 0) { int p = W * 64 + i; if (cum + part[p] >= KPRE) T = p; else cum += part[p]; }
        unsigned P = HS - 1;                     // fewer than KPRE valid -> take all valid
        if (T >= 0)
            for (int j = 0; j < 64; j++) { cum += h[T * 64 + j]; if (cum >= KPRE) { P = (unsigned)(T * 64 + j); break; } }
        cutP = P;
    }
    __syncthreads();
    unsigned P = cutP;

    // ---- phase B: deterministic index-ordered compaction (4 barriers) ----
    const unsigned* kb = k32 + (size_t)b * NBOX;
    unsigned kreg[25];
    unsigned passbits = 0;
    #pragma unroll
    for (int c = 0; c < 25; c++) {               // 25 independent coalesced loads in flight
        int i = c * 1024 + t;
        unsigned k = 0; bool p = false;
        if (i < NBOX) { k = kb[i]; p = ((int)k >= 0) && ((k >> SHIFT) <= P); }
        kreg[c] = k;
        passbits |= (p ? 1u : 0u) << c;
    }
    #pragma unroll
    for (int c = 0; c < 25; c++) {
        unsigned long long m = __ballot((passbits >> c) & 1u);
        if (lane == 0) cnt[c][wv] = (unsigned)__popcll(m);
    }
    __syncthreads();
    if (t < 25) {
        unsigned run = 0;
        #pragma unroll
        for (int w = 0; w < 16; w++) { waveOff[t][w] = run; run += cnt[t][w]; }
        totc[t] = run;
    }
    __syncthreads();
    if (t == 0) {
        unsigned acc = 0;
        for (int c = 0; c < 25; c++) { chunkBase[c] = acc; acc += totc[c]; }
        nTot = acc;
    }
    __syncthreads();
    int n = (int)nTot; if (n > NCAND_MAX) n = NCAND_MAX;
    #pragma unroll
    for (int c = 0; c < 25; c++) {
        unsigned long long m = __ballot((passbits >> c) & 1u);
        if ((passbits >> c) & 1u) {
            unsigned rank = chunkBase[c] + waveOff[c][wv] +
                            (unsigned)__popcll(lane ? (m & ((~0ull) >> (64 - lane))) : 0ull);
            if (rank < NCAND_MAX)
                keys[rank] = ((unsigned long long)kreg[c] << 32) | (unsigned)(c * 1024 + t);
        }
    }
    __syncthreads();

    // ---- phase C: rank-by-count (no barriers; broadcast LDS reads) + argmax/box for winners ----
    int o_b = b << 10;
    for (int ci = t; ci < n; ci += 1024) {
        unsigned long long mykey = keys[ci];
        int rank = 0;
        #pragma unroll 4
        for (int s = 0; s < n; s++) rank += (keys[s] < mykey) ? 1 : 0;
        if (rank < KPRE) {
            int o = o_b + rank;
            unsigned kk = (unsigned)(mykey >> 32);
            unsigned mm = ~kk;
            unsigned bits = (mm & 0x80000000u) ? (mm & 0x7FFFFFFFu) : ~mm;
            topconf[o] = __uint_as_float(bits);          // exact original score
            unsigned idx = (unsigned)(mykey & 0xFFFFFFFFu);
            size_t rb = ((size_t)b * NBOX + idx) * NCH;
            float obj = x[rb + 4];
            float v = -1e30f; int cbest = 0;
            #pragma unroll
            for (int hh = 0; hh < 2; hh++) {
                const float4* p4 = (const float4*)(x + rb + 5 + hh * 40);
                float4 rr[10];
                #pragma unroll
                for (int j = 0; j < 10; j++) rr[j] = p4[j];
                #pragma unroll
                for (int j = 0; j < 10; j++) {           // ascending class order, strict > = first occurrence
                    float s0 = rr[j].x * obj; if (s0 > v) { v = s0; cbest = hh * 40 + j * 4 + 0; }
                    float s1 = rr[j].y * obj; if (s1 > v) { v = s1; cbest = hh * 40 + j * 4 + 1; }
                    float s2 = rr[j].z * obj; if (s2 > v) { v = s2; cbest = hh * 40 + j * 4 + 2; }
                    float s3 = rr[j].w * obj; if (s3 > v) { v = s3; cbest = hh * 40 + j * 4 + 3; }
                }
            }
            float cx = x[rb + 0], cy = x[rb + 1], wd = x[rb + 2], ht = x[rb + 3];
            float4 box = make_float4(cx - wd * 0.5f, cy - ht * 0.5f, cx + wd * 0.5f, cy + ht * 0.5f);
            float clsf = (float)cbest;
            topbox[o] = box;
            topcls[o] = clsf;
            float offv = clsf * 4096.0f;
            topoff[o] = make_float4(box.x + offv, box.y + offv, box.z + offv, box.w + offv);
        }
    }
    // pad slots [n, 1024)
    if (t >= n && t < KPRE) {
        int o = o_b + t;
        topconf[o] = -1.0f;
        topbox[o] = make_float4(0.f, 0.f, 0.f, 0.f);
        topcls[o] = 0.f;
        topoff[o] = make_float4(0.f, 0.f, 0.f, 0.f);
    }
}

// ---------------- kernel 3: pairwise IoU suppression bitmask + per-row summary ----------------
__global__ __launch_bounds__(256) void iou_mask(const float4* __restrict__ topoff,
                                                unsigned long long* __restrict__ mask,
                                                unsigned short* __restrict__ summ) {
#pragma clang fp contract(off)
    __shared__ float4 soff[KPRE];
    int b = blockIdx.x >> 6;
    int blk = blockIdx.x & 63;
    int t = threadIdx.x;
    for (int q = 0; q < 4; q++) {
        int s = t + q * 256;
        soff[s] = topoff[(b << 10) + s];
    }
    __syncthreads();
    int i = (blk << 4) + (t >> 4);
    int w = t & 15;
    unsigned long long bits = 0;
    int jbase = w << 6;
    if (jbase + 63 > i) {                       // lower-triangle words are identically 0
        float4 a = soff[i];
        float area_a = (a.z - a.x) * (a.w - a.y);
        for (int jj = 0; jj < 64; jj++) {
            int j = jbase + jj;
            float4 bb = soff[j];
            float area_b = (bb.z - bb.x) * (bb.w - bb.y);
            float ltx = fmaxf(a.x, bb.x), lty = fmaxf(a.y, bb.y);
            float rbx = fminf(a.z, bb.z), rby = fminf(a.w, bb.w);
            float wx = fmaxf(rbx - ltx, 0.0f), wy = fmaxf(rby - lty, 0.0f);
            float inter = wx * wy;
            float iou = inter / (area_a + area_b - inter + 1e-7f);
            if (j > i && iou > 0.45f) bits |= (1ull << jj);
        }
    }
    mask[((size_t)((b << 10) + i) << 4) + w] = bits;
    unsigned long long bal = __ballot(bits != 0ull);
    if (w == 0) {
        int l = t & 63;
        summ[(b << 10) + i] = (unsigned short)((bal >> ((l >> 4) << 4)) & 0xFFFFull);
    }
}

// ---------------- kernel 4: greedy suppression + ordered output (1 block / batch) ----------------
__global__ __launch_bounds__(1024) void nms_finalize(const unsigned long long* __restrict__ mask,
                                                     const unsigned short* __restrict__ summ,
                                                     const float* __restrict__ topconf,
                                                     const float4* __restrict__ topbox,
                                                     const float* __restrict__ topcls,
                                                     float* __restrict__ dets,
                                                     float* __restrict__ vmask) {
    __shared__ unsigned long long kb[16];
    int b = blockIdx.x, tid = threadIdx.x;

    if (tid < 64) {
        int lane = tid;
        const unsigned long long* mrow = mask + ((size_t)b << 14);
        unsigned long long keep0[16];
        #pragma unroll
        for (int c = 0; c < 16; c++) {
            float cf = topconf[(b << 10) + (c << 6) + lane];
            keep0[c] = __ballot(cf > 0.0f);
        }
        unsigned nz[16];
        #pragma unroll
        for (int t = 0; t < 16; t++)
            nz[t] = (unsigned)summ[(b << 10) + (t << 6) + lane];
        unsigned long long diag[16];
        #pragma unroll
        for (int t = 0; t < 16; t++)
            diag[t] = mrow[((size_t)((t << 6) + lane) << 4) + t];

        unsigned long long remv[16];
        #pragma unroll
        for (int t = 0; t < 16; t++) remv[t] = 0;

        #pragma unroll
        for (int t = 0; t < 16; t++) {
            unsigned long long live = keep0[t] & ~remv[t];
            unsigned long long kept = live;
            unsigned long long pend = live & __ballot((nz[t] >> t) & 1u);
            while (pend) {
                int j = (int)__ffsll(pend) - 1;
                pend &= pend - 1;
                if ((kept >> j) & 1ull) {
                    unsigned long long dj = __shfl(diag[t], j);
                    kept &= ~dj;
                    pend &= ~dj;
                }
            }
            if (lane == 0) kb[t] = kept;

            #pragma unroll
            for (int w = 0; w < 16; w++) {
                if (w > t) {
                    unsigned long long wm = kept & __ballot((nz[t] >> w) & 1u);
                    while (wm) {
                        int j = (int)__ffsll(wm) - 1;
                        wm &= wm - 1;
                        remv[w] |= mrow[((size_t)((t << 6) + j) << 4) + w];
                    }
                }
            }
        }
    }
    __syncthreads();

    int r = tid;
    int w = r >> 6, l = r & 63;
    unsigned long long word = kb[w];
    int keep = (int)((word >> l) & 1ull);
    int base = 0, total = 0;
    #pragma unroll
    for (int q = 0; q < 16; q++) {
        int c = __popcll(kb[q]);
        total += c;
        if (q < w) base += c;
    }
    int rank = base + __popcll((l == 0) ? 0ull : (word & ((~0ull) >> (64 - l))));
    float* drow = dets + (size_t)b * (MAXDET * 6);
    float* vm = vmask + (size_t)b * MAXDET;
    if (r < MAXDET && r >= total) {
#pragma unroll
        for (int cc = 0; cc < 6; cc++) drow[r * 6 + cc] = 0.0f;
        vm[r] = 0.0f;
    }
    if (keep && rank < MAXDET) {
        int o = (b << 10) + r;
        float4 bx = topbox[o];
        drow[rank * 6 + 0] = bx.x;
        drow[rank * 6 + 1] = bx.y;
        drow[rank * 6 + 2] = bx.z;
        drow[rank * 6 + 3] = bx.w;
        drow[rank * 6 + 4] = topconf[o];
        drow[rank * 6 + 5] = topcls[o];
        vm[rank] = 1.0f;
    }
}

// ---------------- launcher ----------------
extern "C" void kernel_launch(void* const* d_in, const int* in_sizes, int n_in,
                              void* d_out, int out_size, void* d_ws, size_t ws_size,
                              hipStream_t stream) {
    const float* x = (const float*)d_in[0];
    char* w = (char*)d_ws;

    // workspace layout (bytes), total 8,592,384
    unsigned long long* mask    = (unsigned long long*)(w + 0);        // 2,097,152
    unsigned*           k32     = (unsigned*)(w + 2097152);            // 1,612,800
    float4*             topbox  = (float4*)(w + 3709952);              // 262,144
    float4*             topoff  = (float4*)(w + 3972096);              // 262,144
    float*              topconf = (float*)(w + 4234240);               // 65,536
    float*              topcls  = (float*)(w + 4299776);               // 65,536
    unsigned short*     summ    = (unsigned short*)(w + 4365312);      // 32,768
    unsigned*           hist    = (unsigned*)(w + 4398080);            // 16*65536*4 = 4,194,304
    if (ws_size < 8592384) return;  // insufficient scratch -> deterministic failure

    int n16 = (BATCH * HS * 4) / 16;
    zero_kernel<<<(n16 + 255) / 256, 256, 0, stream>>>((uint4*)hist, n16);

    score_kernel<<<(BATCH * NBOX * 4) / 256, 256, 0, stream>>>(x, k32, hist);
    mega_front<<<BATCH, 1024, 0, stream>>>(x, k32, hist, topconf, topbox, topoff, topcls);
    iou_mask<<<BATCH * 64, 256, 0, stream>>>(topoff, mask, summ);

    float* dets = (float*)d_out;
    float* vmask = dets + (size_t)BATCH * MAXDET * 6;
    nms_finalize<<<BATCH, 1024, 0, stream>>>(mask, summ, topconf, topbox, topcls, dets, vmask);
}

// Round 14
// 152.447 us; speedup vs baseline: 1.3224x; 1.3224x over previous
//
#include <hip/hip_runtime.h>
#include <cstdint>
#include <cstddef>

// ---------------- problem constants ----------------
#define BATCH 16
#define NBOX 25200
#define NCH 85          // 4 box + 1 obj + 80 cls
#define KPRE 1024
#define MAXDET 1000
#define NCAND_MAX 4096
#define HS 65536        // histogram buckets (key >> 16)
#define SHIFT 16
#define NCHUNK 99       // ceil(NBOX / 256)
#define IDX_PAD 0xFFFFFFFFu

__device__ __forceinline__ unsigned key_of(float s) {
    // monotone map: larger score -> SMALLER key (ascending sort = descending score)
    unsigned u = __float_as_uint(s);
    unsigned m = (u & 0x80000000u) ? ~u : (u | 0x80000000u);
    return ~m;
}

// ---------------- kernel 0: fast workspace zero ----------------
__global__ __launch_bounds__(256) void zero_kernel(uint4* __restrict__ p, int n16) {
    int i = blockIdx.x * 256 + threadIdx.x;
    if (i < n16) p[i] = make_uint4(0u, 0u, 0u, 0u);
}

// ---------------- kernel 1: per-box max-product score + key + histogram ----------------
// (best measured variant: 2 lanes/box, 10 float4 loads, max-only, fine histogram)
__global__ __launch_bounds__(256, 2) void score_kernel(const float* __restrict__ x,
                                                       unsigned* __restrict__ k32,
                                                       unsigned* __restrict__ hist) {
    int gid = blockIdx.x * 256 + threadIdx.x;
    int box = gid >> 1;
    int q = gid & 1;
    size_t base = (size_t)box * NCH;

    float obj = x[base + 4];
    const float4* p = (const float4*)(x + base + 5 + q * 40);
    float4 r[10];
    #pragma unroll
    for (int j = 0; j < 10; j++) r[j] = p[j];   // 10 independent loads in flight

    float v = -1e30f;
    #pragma unroll
    for (int j = 0; j < 10; j++) {              // max of products; value order-invariant
        float m0 = fmaxf(r[j].x * obj, r[j].y * obj);
        float m1 = fmaxf(r[j].z * obj, r[j].w * obj);
        v = fmaxf(v, fmaxf(m0, m1));
    }
    v = fmaxf(v, __shfl_xor(v, 1));             // combine halves

    if (q == 0) {
        bool validb = (obj > 0.25f) && (v > 0.25f);
        float score = validb ? v : -1.0f;
        unsigned k = key_of(score);
        k32[box] = k;
        if (validb) {
            int b = box / NBOX;
            atomicAdd(&hist[b * HS + (int)(k >> SHIFT)], 1u);  // commutative -> deterministic
        }
    }
}

// ---------------- kernel 2: histogram cutoff covering rank KPRE (1024 thr, uint4) ----------------
__global__ __launch_bounds__(1024) void select_cutoff(const unsigned* __restrict__ hist,
                                                      unsigned* __restrict__ cutoff) {
    __shared__ unsigned part[1024];
    __shared__ unsigned wsum[16];
    int b = blockIdx.x, t = threadIdx.x;
    int lane = t & 63, wv = t >> 6;
    const unsigned* h = hist + (size_t)b * HS;
    const uint4* h4 = (const uint4*)(h + t * 64);
    unsigned s = 0;
    #pragma unroll
    for (int j = 0; j < 16; j++) { uint4 v4 = h4[j]; s += v4.x + v4.y + v4.z + v4.w; }
    part[t] = s;
    unsigned ws = s;
    #pragma unroll
    for (int off = 1; off < 64; off <<= 1) ws += __shfl_xor(ws, off);
    if (lane == 0) wsum[wv] = ws;
    __syncthreads();
    if (t == 0) {
        unsigned cum = 0; int W = -1;
        for (int w = 0; w < 16; w++)
            if (W < 0) { if (cum + wsum[w] >= KPRE) W = w; else cum += wsum[w]; }
        int T = -1;
        if (W >= 0)
            for (int i = 0; i < 64; i++)
                if (T < 0) { int p = W * 64 + i; if (cum + part[p] >= KPRE) T = p; else cum += part[p]; }
        unsigned P = HS - 1;                     // fewer than KPRE valid -> take all valid
        if (T >= 0)
            for (int j = 0; j < 64; j++) { cum += h[T * 64 + j]; if (cum >= KPRE) { P = (unsigned)(T * 64 + j); break; } }
        cutoff[b] = P;
    }
}

// ---------------- kernels 3a/3b/3c: DETERMINISTIC candidate compaction ----------------
__device__ __forceinline__ bool cand_pass(const unsigned* k32, const unsigned* cutoff,
                                          int b, int i, unsigned& k) {
    if (i >= NBOX) return false;
    k = k32[(size_t)b * NBOX + i];
    return ((int)k >= 0) && ((k >> SHIFT) <= cutoff[b]);  // sign bit set = invalid
}

__global__ __launch_bounds__(256) void count_kernel(const unsigned* __restrict__ k32,
                                                    const unsigned* __restrict__ cutoff,
                                                    unsigned* __restrict__ chunkCnt) {
    int b = blockIdx.y, chunk = blockIdx.x;
    int i = chunk * 256 + threadIdx.x;
    unsigned k;
    bool pass = cand_pass(k32, cutoff, b, i, k);
    unsigned long long m = __ballot(pass);
    __shared__ unsigned wc[4];
    int lane = threadIdx.x & 63, wid = threadIdx.x >> 6;
    if (lane == 0) wc[wid] = (unsigned)__popcll(m);
    __syncthreads();
    if (threadIdx.x == 0) chunkCnt[b * NCHUNK + chunk] = wc[0] + wc[1] + wc[2] + wc[3];
}

__global__ __launch_bounds__(128) void scan_kernel(unsigned* __restrict__ chunkCnt,
                                                   unsigned* __restrict__ ncand) {
    int b = blockIdx.x, t = threadIdx.x;
    __shared__ unsigned s[128];
    unsigned v = (t < NCHUNK) ? chunkCnt[b * NCHUNK + t] : 0u;
    s[t] = v;
    __syncthreads();
    #pragma unroll
    for (int off = 1; off < 128; off <<= 1) {
        unsigned u = (t >= off) ? s[t - off] : 0u;
        __syncthreads();
        s[t] += u;
        __syncthreads();
    }
    if (t < NCHUNK) chunkCnt[b * NCHUNK + t] = s[t] - v;   // exclusive
    if (t == NCHUNK - 1) ncand[b] = s[t];
}

__global__ __launch_bounds__(256) void place_kernel(const unsigned* __restrict__ k32,
                                                    const unsigned* __restrict__ cutoff,
                                                    const unsigned* __restrict__ chunkCnt,
                                                    unsigned long long* __restrict__ cand) {
    int b = blockIdx.y, chunk = blockIdx.x;
    int i = chunk * 256 + threadIdx.x;
    unsigned k = 0;
    bool pass = cand_pass(k32, cutoff, b, i, k);
    unsigned long long m = __ballot(pass);
    __shared__ unsigned wc[4];
    int lane = threadIdx.x & 63, wid = threadIdx.x >> 6;
    if (lane == 0) wc[wid] = (unsigned)__popcll(m);
    __syncthreads();
    unsigned base = chunkCnt[b * NCHUNK + chunk];
    base += (wid > 0 ? wc[0] : 0u) + (wid > 1 ? wc[1] : 0u) + (wid > 2 ? wc[2] : 0u);
    unsigned rank = base + (unsigned)__popcll(lane ? (m & ((~0ull) >> (64 - lane))) : 0ull);
    if (pass && rank < NCAND_MAX)
        cand[(size_t)b * NCAND_MAX + rank] = ((unsigned long long)k << 32) | (unsigned)i;
}

// ---------------- kernel 4: bitonic sort candidates (dynamic size) -> topconf/topidx ----------------
__global__ __launch_bounds__(1024) void sort_gather(const unsigned long long* __restrict__ cand,
                                                    const unsigned* __restrict__ ncand,
                                                    float* __restrict__ topconf,
                                                    unsigned* __restrict__ topidx) {
    __shared__ unsigned long long keys[NCAND_MAX];
    int b = blockIdx.x, t = threadIdx.x;
    int n = (int)ncand[b];
    if (n > NCAND_MAX) n = NCAND_MAX;
    int m = KPRE;
    while (m < n) m <<= 1;
    int nq = m >> 10;
    for (int q = 0; q < nq; q++) {
        int s = t + (q << 10);
        keys[s] = (s < n) ? cand[(size_t)b * NCAND_MAX + s] : ~0ull;
    }
    __syncthreads();
    // ascending bitonic sort: key ascending = score descending, ties by ascending idx
    for (int k = 2; k <= m; k <<= 1) {
        for (int j = k >> 1; j > 0; j >>= 1) {
            for (int q = 0; q < nq; q++) {
                int i = t + (q << 10);
                int ixj = i ^ j;
                if (ixj > i) {
                    unsigned long long a = keys[i], bb = keys[ixj];
                    bool up = ((i & k) == 0);
                    if ((a > bb) == up) { keys[i] = bb; keys[ixj] = a; }
                }
            }
            __syncthreads();
        }
    }
    int o = (b << 10) + t;
    if (t < n) {
        unsigned long long key = keys[t];
        unsigned kk = (unsigned)(key >> 32);
        unsigned mm = ~kk;
        unsigned bits = (mm & 0x80000000u) ? (mm & 0x7FFFFFFFu) : ~mm;
        topconf[o] = __uint_as_float(bits);     // exact original score
        topidx[o] = (unsigned)(key & 0xFFFFFFFFu);
    } else {
        topconf[o] = -1.0f;
        topidx[o] = IDX_PAD;
    }
}

// ---------------- kernel 4b: exact argmax + box build for the 16K survivors only ----------------
__global__ __launch_bounds__(256) void argmax_gather(const float* __restrict__ x,
                                                     const unsigned* __restrict__ topidx,
                                                     float4* __restrict__ topbox,
                                                     float4* __restrict__ topoff,
                                                     float* __restrict__ topcls) {
#pragma clang fp contract(off)
    int gid = blockIdx.x * 256 + threadIdx.x;
    int o = gid >> 2;                           // entry in [0, BATCH*KPRE)
    int q = gid & 3;
    int b = o >> 10;
    unsigned idx = topidx[o];

    float4 box = make_float4(0.f, 0.f, 0.f, 0.f);
    float clsf = 0.f;
    if (idx != IDX_PAD) {
        size_t base = ((size_t)b * NBOX + idx) * NCH;
        float obj = x[base + 4];
        int cbase = 5 + q * 20;
        float v = -1e30f; int c = 0;
        #pragma unroll
        for (int j = 0; j < 20; j++) {
            float s = x[base + cbase + j] * obj;
            if (s > v) { v = s; c = q * 20 + j; }      // strict > = first occurrence
        }
        #pragma unroll
        for (int off = 1; off <= 2; off <<= 1) {
            float ov = __shfl_xor(v, off);
            int   oc = __shfl_xor(c, off);
            if (ov > v || (ov == v && oc < c)) { v = ov; c = oc; }
        }
        if (q == 0) {
            float cx = x[base + 0], cy = x[base + 1], w = x[base + 2], h = x[base + 3];
            box = make_float4(cx - w * 0.5f, cy - h * 0.5f, cx + w * 0.5f, cy + h * 0.5f);
            clsf = (float)c;
        }
    }
    if (q == 0) {
        topbox[o] = box;
        topcls[o] = clsf;
        float off = clsf * 4096.0f;
        topoff[o] = make_float4(box.x + off, box.y + off, box.z + off, box.w + off);
    }
}

// ---------------- kernel 5: pairwise IoU bitmask, TRANSPOSED LDS (kills 16-way conflicts) ----------------
// Box j stored at LDS slot ((j&63)<<4)|(j>>6). Inner-loop read slot (jj<<4)|w ->
// bank start 4w%32: 2-way + broadcast = free (was: all 16 w on ONE bank-quad).
__global__ __launch_bounds__(256) void iou_mask(const float4* __restrict__ topoff,
                                                unsigned long long* __restrict__ mask,
                                                unsigned short* __restrict__ summ) {
#pragma clang fp contract(off)
    __shared__ float4 soff[KPRE];
    int b = blockIdx.x >> 6;
    int blk = blockIdx.x & 63;
    int t = threadIdx.x;
    // contiguous LDS slots (no write conflict); permuted global read still 16 lines/instr
    for (int q = 0; q < 4; q++) {
        int u = t + q * 256;                       // LDS slot
        int s = ((u & 15) << 6) | (u >> 4);        // source box = invperm(u)
        soff[u] = topoff[(b << 10) + s];
    }
    __syncthreads();
    int i = (blk << 4) + (t >> 4);
    int w = t & 15;
    unsigned long long bits = 0;
    int jbase = w << 6;
    if (jbase + 63 > i) {                          // lower-triangle words are identically 0
        float4 a = soff[((i & 63) << 4) | (i >> 6)];
        float area_a = (a.z - a.x) * (a.w - a.y);
        for (int jj = 0; jj < 64; jj++) {
            int j = jbase + jj;
            float4 bb = soff[(jj << 4) | w];       // transposed slot for box j
            float area_b = (bb.z - bb.x) * (bb.w - bb.y);
            float ltx = fmaxf(a.x, bb.x), lty = fmaxf(a.y, bb.y);
            float rbx = fminf(a.z, bb.z), rby = fminf(a.w, bb.w);
            float wx = fmaxf(rbx - ltx, 0.0f), wy = fmaxf(rby - lty, 0.0f);
            float inter = wx * wy;
            float iou = inter / (area_a + area_b - inter + 1e-7f);
            if (j > i && iou > 0.45f) bits |= (1ull << jj);
        }
    }
    mask[((size_t)((b << 10) + i) << 4) + w] = bits;
    unsigned long long bal = __ballot(bits != 0ull);
    if (w == 0) {
        int l = t & 63;
        summ[(b << 10) + i] = (unsigned short)((bal >> ((l >> 4) << 4)) & 0xFFFFull);
    }
}

// ---------------- kernel 6: greedy suppression + ordered output (1 block / batch) ----------------
__global__ __launch_bounds__(1024) void nms_finalize(const unsigned long long* __restrict__ mask,
                                                     const unsigned short* __restrict__ summ,
                                                     const float* __restrict__ topconf,
                                                     const float4* __restrict__ topbox,
                                                     const float* __restrict__ topcls,
                                                     float* __restrict__ dets,
                                                     float* __restrict__ vmask) {
    __shared__ unsigned long long kb[16];
    int b = blockIdx.x, tid = threadIdx.x;

    if (tid < 64) {
        int lane = tid;
        const unsigned long long* mrow = mask + ((size_t)b << 14);
        unsigned long long keep0[16];
        #pragma unroll
        for (int c = 0; c < 16; c++) {
            float cf = topconf[(b << 10) + (c << 6) + lane];
            keep0[c] = __ballot(cf > 0.0f);
        }
        unsigned nz[16];
        #pragma unroll
        for (int t = 0; t < 16; t++)
            nz[t] = (unsigned)summ[(b << 10) + (t << 6) + lane];
        unsigned long long diag[16];
        #pragma unroll
        for (int t = 0; t < 16; t++)
            diag[t] = mrow[((size_t)((t << 6) + lane) << 4) + t];

        unsigned long long remv[16];
        #pragma unroll
        for (int t = 0; t < 16; t++) remv[t] = 0;

        #pragma unroll
        for (int t = 0; t < 16; t++) {
            unsigned long long live = keep0[t] & ~remv[t];
            unsigned long long kept = live;
            unsigned long long pend = live & __ballot((nz[t] >> t) & 1u);
            while (pend) {
                int j = (int)__ffsll(pend) - 1;
                pend &= pend - 1;
                if ((kept >> j) & 1ull) {
                    unsigned long long dj = __shfl(diag[t], j);
                    kept &= ~dj;
                    pend &= ~dj;
                }
            }
            if (lane == 0) kb[t] = kept;

            #pragma unroll
            for (int w = 0; w < 16; w++) {
                if (w > t) {
                    unsigned long long wm = kept & __ballot((nz[t] >> w) & 1u);
                    while (wm) {
                        int j = (int)__ffsll(wm) - 1;
                        wm &= wm - 1;
                        remv[w] |= mrow[((size_t)((t << 6) + j) << 4) + w];
                    }
                }
            }
        }
    }
    __syncthreads();

    int r = tid;
    int w = r >> 6, l = r & 63;
    unsigned long long word = kb[w];
    int keep = (int)((word >> l) & 1ull);
    int base = 0, total = 0;
    #pragma unroll
    for (int q = 0; q < 16; q++) {
        int c = __popcll(kb[q]);
        total += c;
        if (q < w) base += c;
    }
    int rank = base + __popcll((l == 0) ? 0ull : (word & ((~0ull) >> (64 - l))));
    float* drow = dets + (size_t)b * (MAXDET * 6);
    float* vm = vmask + (size_t)b * MAXDET;
    if (r < MAXDET && r >= total) {
#pragma unroll
        for (int cc = 0; cc < 6; cc++) drow[r * 6 + cc] = 0.0f;
        vm[r] = 0.0f;
    }
    if (keep && rank < MAXDET) {
        int o = (b << 10) + r;
        float4 bx = topbox[o];
        drow[rank * 6 + 0] = bx.x;
        drow[rank * 6 + 1] = bx.y;
        drow[rank * 6 + 2] = bx.z;
        drow[rank * 6 + 3] = bx.w;
        drow[rank * 6 + 4] = topconf[o];
        drow[rank * 6 + 5] = topcls[o];
        vm[rank] = 1.0f;
    }
}

// ---------------- launcher ----------------
extern "C" void kernel_launch(void* const* d_in, const int* in_sizes, int n_in,
                              void* d_out, int out_size, void* d_ws, size_t ws_size,
                              hipStream_t stream) {
    const float* x = (const float*)d_in[0];
    char* w = (char*)d_ws;

    // workspace layout (bytes), total 9,188,672
    unsigned long long* cand     = (unsigned long long*)(w + 0);        // 524288
    unsigned long long* mask     = (unsigned long long*)(w + 524288);   // 2097152
    unsigned*           k32      = (unsigned*)(w + 2621440);            // 1612800
    float4*             topbox   = (float4*)(w + 4234240);              // 262144
    float4*             topoff   = (float4*)(w + 4496384);              // 262144
    float*              topconf  = (float*)(w + 4758528);               // 65536
    float*              topcls   = (float*)(w + 4824064);               // 65536
    unsigned*           topidx   = (unsigned*)(w + 4889600);            // 65536
    unsigned*           cutoff   = (unsigned*)(w + 4955136);            // 64
    unsigned*           ncand    = (unsigned*)(w + 4955200);            // 64
    unsigned short*     summ     = (unsigned short*)(w + 4955264);      // 32768
    unsigned*           chunkCnt = (unsigned*)(w + 4988032);            // 6336
    unsigned*           hist     = (unsigned*)(w + 4994368);            // 16*65536*4 = 4194304
    if (ws_size < 9188672) return;  // insufficient scratch -> deterministic failure

    int n16 = (BATCH * HS * 4) / 16;
    zero_kernel<<<(n16 + 255) / 256, 256, 0, stream>>>((uint4*)hist, n16);

    score_kernel<<<(BATCH * NBOX * 2) / 256, 256, 0, stream>>>(x, k32, hist);
    select_cutoff<<<BATCH, 1024, 0, stream>>>(hist, cutoff);
    count_kernel<<<dim3(NCHUNK, BATCH), 256, 0, stream>>>(k32, cutoff, chunkCnt);
    scan_kernel<<<BATCH, 128, 0, stream>>>(chunkCnt, ncand);
    place_kernel<<<dim3(NCHUNK, BATCH), 256, 0, stream>>>(k32, cutoff, chunkCnt, cand);
    sort_gather<<<BATCH, 1024, 0, stream>>>(cand, ncand, topconf, topidx);
    argmax_gather<<<(BATCH * KPRE * 4) / 256, 256, 0, stream>>>(x, topidx, topbox, topoff, topcls);
    iou_mask<<<BATCH * 64, 256, 0, stream>>>(topoff, mask, summ);

    float* dets = (float*)d_out;
    float* vmask = dets + (size_t)BATCH * MAXDET * 6;
    nms_finalize<<<BATCH, 1024, 0, stream>>>(mask, summ, topconf, topbox, topcls, dets, vmask);
}

// Round 15
// 149.917 us; speedup vs baseline: 1.3447x; 1.0169x over previous
//
#include <hip/hip_runtime.h>
#include <cstdint>
#include <cstddef>

// ---------------- problem constants ----------------
#define BATCH 16
#define NBOX 25200
#define NCH 85          // 4 box + 1 obj + 80 cls
#define KPRE 1024
#define MAXDET 1000
#define NCAND_MAX 4096
#define HS 65536        // histogram buckets (key >> 16)
#define SHIFT 16
#define IDX_PAD 0xFFFFFFFFu

__device__ __forceinline__ unsigned key_of(float s) {
    // monotone map: larger score -> SMALLER key (ascending sort = descending score)
    unsigned u = __float_as_uint(s);
    unsigned m = (u & 0x80000000u) ? ~u : (u | 0x80000000u);
    return ~m;
}

// ---------------- kernel 0: fast workspace zero ----------------
__global__ __launch_bounds__(256) void zero_kernel(uint4* __restrict__ p, int n16) {
    int i = blockIdx.x * 256 + threadIdx.x;
    if (i < n16) p[i] = make_uint4(0u, 0u, 0u, 0u);
}

// ---------------- kernel 1: per-box max-product score + key + histogram ----------------
// (best measured variant: 2 lanes/box, 10 float4 loads, max-only, fine histogram)
__global__ __launch_bounds__(256, 2) void score_kernel(const float* __restrict__ x,
                                                       unsigned* __restrict__ k32,
                                                       unsigned* __restrict__ hist) {
    int gid = blockIdx.x * 256 + threadIdx.x;
    int box = gid >> 1;
    int q = gid & 1;
    size_t base = (size_t)box * NCH;

    float obj = x[base + 4];
    const float4* p = (const float4*)(x + base + 5 + q * 40);
    float4 r[10];
    #pragma unroll
    for (int j = 0; j < 10; j++) r[j] = p[j];   // 10 independent loads in flight

    float v = -1e30f;
    #pragma unroll
    for (int j = 0; j < 10; j++) {              // max of products; value order-invariant
        float m0 = fmaxf(r[j].x * obj, r[j].y * obj);
        float m1 = fmaxf(r[j].z * obj, r[j].w * obj);
        v = fmaxf(v, fmaxf(m0, m1));
    }
    v = fmaxf(v, __shfl_xor(v, 1));             // combine halves

    if (q == 0) {
        bool validb = (obj > 0.25f) && (v > 0.25f);
        float score = validb ? v : -1.0f;
        unsigned k = key_of(score);
        k32[box] = k;
        if (validb) {
            int b = box / NBOX;
            atomicAdd(&hist[b * HS + (int)(k >> SHIFT)], 1u);  // commutative -> deterministic
        }
    }
}

// ---------------- kernel 2: histogram cutoff covering rank KPRE (1024 thr, uint4) ----------------
__global__ __launch_bounds__(1024) void select_cutoff(const unsigned* __restrict__ hist,
                                                      unsigned* __restrict__ cutoff) {
    __shared__ unsigned part[1024];
    __shared__ unsigned wsum[16];
    int b = blockIdx.x, t = threadIdx.x;
    int lane = t & 63, wv = t >> 6;
    const unsigned* h = hist + (size_t)b * HS;
    const uint4* h4 = (const uint4*)(h + t * 64);
    unsigned s = 0;
    #pragma unroll
    for (int j = 0; j < 16; j++) { uint4 v4 = h4[j]; s += v4.x + v4.y + v4.z + v4.w; }
    part[t] = s;
    unsigned ws = s;
    #pragma unroll
    for (int off = 1; off < 64; off <<= 1) ws += __shfl_xor(ws, off);
    if (lane == 0) wsum[wv] = ws;
    __syncthreads();
    if (t == 0) {
        unsigned cum = 0; int W = -1;
        for (int w = 0; w < 16; w++)
            if (W < 0) { if (cum + wsum[w] >= KPRE) W = w; else cum += wsum[w]; }
        int T = -1;
        if (W >= 0)
            for (int i = 0; i < 64; i++)
                if (T < 0) { int p = W * 64 + i; if (cum + part[p] >= KPRE) T = p; else cum += part[p]; }
        unsigned P = HS - 1;                     // fewer than KPRE valid -> take all valid
        if (T >= 0)
            for (int j = 0; j < 64; j++) { cum += h[T * 64 + j]; if (cum >= KPRE) { P = (unsigned)(T * 64 + j); break; } }
        cutoff[b] = P;
    }
}

// ---------------- kernel 3: fused compaction + bitonic sort + decode (1 block / batch) ----------------
// Deterministic index-ordered compaction straight from k32 into LDS (ballot count matrix,
// 4 barriers — proven in R12/R13), then the dynamic-size bitonic and rank decode.
__global__ __launch_bounds__(1024) void sort_gather(const unsigned* __restrict__ k32,
                                                    const unsigned* __restrict__ cutoff,
                                                    float* __restrict__ topconf,
                                                    unsigned* __restrict__ topidx) {
    __shared__ unsigned long long keys[NCAND_MAX];   // 32 KB
    __shared__ unsigned cnt[25][16];
    __shared__ unsigned waveOff[25][16];
    __shared__ unsigned chunkBase[25];
    __shared__ unsigned totc[25];
    __shared__ unsigned nTot;
    int b = blockIdx.x, t = threadIdx.x;
    int lane = t & 63, wv = t >> 6;
    unsigned P = cutoff[b];
    const unsigned* kb = k32 + (size_t)b * NBOX;

    // ---- compaction: 25 chunks of 1024, all loads in flight, ballot count matrix ----
    unsigned kreg[25];
    unsigned passbits = 0;
    #pragma unroll
    for (int c = 0; c < 25; c++) {
        int i = c * 1024 + t;
        unsigned k = 0; bool p = false;
        if (i < NBOX) { k = kb[i]; p = ((int)k >= 0) && ((k >> SHIFT) <= P); }
        kreg[c] = k;
        passbits |= (p ? 1u : 0u) << c;
    }
    #pragma unroll
    for (int c = 0; c < 25; c++) {
        unsigned long long m = __ballot((passbits >> c) & 1u);
        if (lane == 0) cnt[c][wv] = (unsigned)__popcll(m);
    }
    __syncthreads();
    if (t < 25) {
        unsigned run = 0;
        #pragma unroll
        for (int w2 = 0; w2 < 16; w2++) { waveOff[t][w2] = run; run += cnt[t][w2]; }
        totc[t] = run;
    }
    __syncthreads();
    if (t == 0) {
        unsigned acc = 0;
        for (int c = 0; c < 25; c++) { chunkBase[c] = acc; acc += totc[c]; }
        nTot = acc;
    }
    __syncthreads();
    int n = (int)nTot; if (n > NCAND_MAX) n = NCAND_MAX;
    #pragma unroll
    for (int c = 0; c < 25; c++) {
        unsigned long long m = __ballot((passbits >> c) & 1u);
        if ((passbits >> c) & 1u) {
            unsigned rank = chunkBase[c] + waveOff[c][wv] +
                            (unsigned)__popcll(lane ? (m & ((~0ull) >> (64 - lane))) : 0ull);
            if (rank < NCAND_MAX)
                keys[rank] = ((unsigned long long)kreg[c] << 32) | (unsigned)(c * 1024 + t);
        }
    }
    int m2 = KPRE;
    while (m2 < n) m2 <<= 1;
    int nq = m2 >> 10;
    for (int q = 0; q < nq; q++) { int s2 = t + (q << 10); if (s2 >= n) keys[s2] = ~0ull; }
    __syncthreads();

    // ---- ascending bitonic sort: key ascending = score descending, ties by ascending idx ----
    for (int k = 2; k <= m2; k <<= 1) {
        for (int j = k >> 1; j > 0; j >>= 1) {
            for (int q = 0; q < nq; q++) {
                int i = t + (q << 10);
                int ixj = i ^ j;
                if (ixj > i) {
                    unsigned long long a = keys[i], bb = keys[ixj];
                    bool up = ((i & k) == 0);
                    if ((a > bb) == up) { keys[i] = bb; keys[ixj] = a; }
                }
            }
            __syncthreads();
        }
    }

    // ---- decode rank t ----
    int o = (b << 10) + t;
    if (t < n) {
        unsigned long long key = keys[t];
        unsigned kk = (unsigned)(key >> 32);
        unsigned mm = ~kk;
        unsigned bits = (mm & 0x80000000u) ? (mm & 0x7FFFFFFFu) : ~mm;
        topconf[o] = __uint_as_float(bits);     // exact original score
        topidx[o] = (unsigned)(key & 0xFFFFFFFFu);
    } else {
        topconf[o] = -1.0f;
        topidx[o] = IDX_PAD;
    }
}

// ---------------- kernel 4: exact argmax + box build for the 16K survivors only ----------------
__global__ __launch_bounds__(256) void argmax_gather(const float* __restrict__ x,
                                                     const unsigned* __restrict__ topidx,
                                                     float4* __restrict__ topbox,
                                                     float4* __restrict__ topoff,
                                                     float* __restrict__ topcls) {
#pragma clang fp contract(off)
    int gid = blockIdx.x * 256 + threadIdx.x;
    int o = gid >> 2;                           // entry in [0, BATCH*KPRE)
    int q = gid & 3;
    int b = o >> 10;
    unsigned idx = topidx[o];

    float4 box = make_float4(0.f, 0.f, 0.f, 0.f);
    float clsf = 0.f;
    if (idx != IDX_PAD) {
        size_t base = ((size_t)b * NBOX + idx) * NCH;
        float obj = x[base + 4];
        int cbase = 5 + q * 20;
        float v = -1e30f; int c = 0;
        #pragma unroll
        for (int j = 0; j < 20; j++) {
            float s = x[base + cbase + j] * obj;
            if (s > v) { v = s; c = q * 20 + j; }      // strict > = first occurrence
        }
        #pragma unroll
        for (int off = 1; off <= 2; off <<= 1) {
            float ov = __shfl_xor(v, off);
            int   oc = __shfl_xor(c, off);
            if (ov > v || (ov == v && oc < c)) { v = ov; c = oc; }
        }
        if (q == 0) {
            float cx = x[base + 0], cy = x[base + 1], w = x[base + 2], h = x[base + 3];
            box = make_float4(cx - w * 0.5f, cy - h * 0.5f, cx + w * 0.5f, cy + h * 0.5f);
            clsf = (float)c;
        }
    }
    if (q == 0) {
        topbox[o] = box;
        topcls[o] = clsf;
        float off = clsf * 4096.0f;
        topoff[o] = make_float4(box.x + off, box.y + off, box.z + off, box.w + off);
    }
}

// ---------------- kernel 5: pairwise IoU bitmask, TRANSPOSED LDS (conflict-free) ----------------
__global__ __launch_bounds__(256) void iou_mask(const float4* __restrict__ topoff,
                                                unsigned long long* __restrict__ mask,
                                                unsigned short* __restrict__ summ) {
#pragma clang fp contract(off)
    __shared__ float4 soff[KPRE];
    int b = blockIdx.x >> 6;
    int blk = blockIdx.x & 63;
    int t = threadIdx.x;
    // contiguous LDS slots (no write conflict); permuted global read still 16 lines/instr
    for (int q = 0; q < 4; q++) {
        int u = t + q * 256;                       // LDS slot
        int s = ((u & 15) << 6) | (u >> 4);        // source box = invperm(u)
        soff[u] = topoff[(b << 10) + s];
    }
    __syncthreads();
    int i = (blk << 4) + (t >> 4);
    int w = t & 15;
    unsigned long long bits = 0;
    int jbase = w << 6;
    if (jbase + 63 > i) {                          // lower-triangle words are identically 0
        float4 a = soff[((i & 63) << 4) | (i >> 6)];
        float area_a = (a.z - a.x) * (a.w - a.y);
        for (int jj = 0; jj < 64; jj++) {
            int j = jbase + jj;
            float4 bb = soff[(jj << 4) | w];       // transposed slot for box j
            float area_b = (bb.z - bb.x) * (bb.w - bb.y);
            float ltx = fmaxf(a.x, bb.x), lty = fmaxf(a.y, bb.y);
            float rbx = fminf(a.z, bb.z), rby = fminf(a.w, bb.w);
            float wx = fmaxf(rbx - ltx, 0.0f), wy = fmaxf(rby - lty, 0.0f);
            float inter = wx * wy;
            float iou = inter / (area_a + area_b - inter + 1e-7f);
            if (j > i && iou > 0.45f) bits |= (1ull << jj);
        }
    }
    mask[((size_t)((b << 10) + i) << 4) + w] = bits;
    unsigned long long bal = __ballot(bits != 0ull);
    if (w == 0) {
        int l = t & 63;
        summ[(b << 10) + i] = (unsigned short)((bal >> ((l >> 4) << 4)) & 0xFFFFull);
    }
}

// ---------------- kernel 6: greedy suppression + ordered output (1 block / batch) ----------------
__global__ __launch_bounds__(1024) void nms_finalize(const unsigned long long* __restrict__ mask,
                                                     const unsigned short* __restrict__ summ,
                                                     const float* __restrict__ topconf,
                                                     const float4* __restrict__ topbox,
                                                     const float* __restrict__ topcls,
                                                     float* __restrict__ dets,
                                                     float* __restrict__ vmask) {
    __shared__ unsigned long long kb[16];
    int b = blockIdx.x, tid = threadIdx.x;

    if (tid < 64) {
        int lane = tid;
        const unsigned long long* mrow = mask + ((size_t)b << 14);
        unsigned long long keep0[16];
        #pragma unroll
        for (int c = 0; c < 16; c++) {
            float cf = topconf[(b << 10) + (c << 6) + lane];
            keep0[c] = __ballot(cf > 0.0f);
        }
        unsigned nz[16];
        #pragma unroll
        for (int t = 0; t < 16; t++)
            nz[t] = (unsigned)summ[(b << 10) + (t << 6) + lane];
        unsigned long long diag[16];
        #pragma unroll
        for (int t = 0; t < 16; t++)
            diag[t] = mrow[((size_t)((t << 6) + lane) << 4) + t];

        unsigned long long remv[16];
        #pragma unroll
        for (int t = 0; t < 16; t++) remv[t] = 0;

        #pragma unroll
        for (int t = 0; t < 16; t++) {
            unsigned long long live = keep0[t] & ~remv[t];
            unsigned long long kept = live;
            unsigned long long pend = live & __ballot((nz[t] >> t) & 1u);
            while (pend) {
                int j = (int)__ffsll(pend) - 1;
                pend &= pend - 1;
                if ((kept >> j) & 1ull) {
                    unsigned long long dj = __shfl(diag[t], j);
                    kept &= ~dj;
                    pend &= ~dj;
                }
            }
            if (lane == 0) kb[t] = kept;

            #pragma unroll
            for (int w = 0; w < 16; w++) {
                if (w > t) {
                    unsigned long long wm = kept & __ballot((nz[t] >> w) & 1u);
                    while (wm) {
                        int j = (int)__ffsll(wm) - 1;
                        wm &= wm - 1;
                        remv[w] |= mrow[((size_t)((t << 6) + j) << 4) + w];
                    }
                }
            }
        }
    }
    __syncthreads();

    int r = tid;
    int w = r >> 6, l = r & 63;
    unsigned long long word = kb[w];
    int keep = (int)((word >> l) & 1ull);
    int base = 0, total = 0;
    #pragma unroll
    for (int q = 0; q < 16; q++) {
        int c = __popcll(kb[q]);
        total += c;
        if (q < w) base += c;
    }
    int rank = base + __popcll((l == 0) ? 0ull : (word & ((~0ull) >> (64 - l))));
    float* drow = dets + (size_t)b * (MAXDET * 6);
    float* vm = vmask + (size_t)b * MAXDET;
    if (r < MAXDET && r >= total) {
#pragma unroll
        for (int cc = 0; cc < 6; cc++) drow[r * 6 + cc] = 0.0f;
        vm[r] = 0.0f;
    }
    if (keep && rank < MAXDET) {
        int o = (b << 10) + r;
        float4 bx = topbox[o];
        drow[rank * 6 + 0] = bx.x;
        drow[rank * 6 + 1] = bx.y;
        drow[rank * 6 + 2] = bx.z;
        drow[rank * 6 + 3] = bx.w;
        drow[rank * 6 + 4] = topconf[o];
        drow[rank * 6 + 5] = topcls[o];
        vm[rank] = 1.0f;
    }
}

// ---------------- launcher ----------------
extern "C" void kernel_launch(void* const* d_in, const int* in_sizes, int n_in,
                              void* d_out, int out_size, void* d_ws, size_t ws_size,
                              hipStream_t stream) {
    const float* x = (const float*)d_in[0];
    char* w = (char*)d_ws;

    // workspace layout (bytes), total 8,658,112
    unsigned long long* mask    = (unsigned long long*)(w + 0);        // 2,097,152
    unsigned*           k32     = (unsigned*)(w + 2097152);            // 1,612,800
    float4*             topbox  = (float4*)(w + 3709952);              // 262,144
    float4*             topoff  = (float4*)(w + 3972096);              // 262,144
    float*              topconf = (float*)(w + 4234240);               // 65,536
    float*              topcls  = (float*)(w + 4299776);               // 65,536
    unsigned*           topidx  = (unsigned*)(w + 4365312);            // 65,536
    unsigned*           cutoff  = (unsigned*)(w + 4430848);            // 64
    unsigned short*     summ    = (unsigned short*)(w + 4430912);      // 32,768
    unsigned*           hist    = (unsigned*)(w + 4463808);            // 16*65536*4 = 4,194,304
    if (ws_size < 8658112) return;  // insufficient scratch -> deterministic failure

    int n16 = (BATCH * HS * 4) / 16;
    zero_kernel<<<(n16 + 255) / 256, 256, 0, stream>>>((uint4*)hist, n16);

    score_kernel<<<(BATCH * NBOX * 2) / 256, 256, 0, stream>>>(x, k32, hist);
    select_cutoff<<<BATCH, 1024, 0, stream>>>(hist, cutoff);
    sort_gather<<<BATCH, 1024, 0, stream>>>(k32, cutoff, topconf, topidx);
    argmax_gather<<<(BATCH * KPRE * 4) / 256, 256, 0, stream>>>(x, topidx, topbox, topoff, topcls);
    iou_mask<<<BATCH * 64, 256, 0, stream>>>(topoff, mask, summ);

    float* dets = (float*)d_out;
    float* vmask = dets + (size_t)BATCH * MAXDET * 6;
    nms_finalize<<<BATCH, 1024, 0, stream>>>(mask, summ, topconf, topbox, topcls, dets, vmask);
}

// Round 16
// 111.340 us; speedup vs baseline: 1.8106x; 1.3465x over previous
//
#include <hip/hip_runtime.h>
#include <cstdint>
#include <cstddef>

// ---------------- problem constants ----------------
#define BATCH 16
#define NBOX 25200
#define NCH 85          // 4 box + 1 obj + 80 cls
#define KPRE 1024
#define MAXDET 1000
#define NCAND_MAX 4096
#define CSHIFT 12       // cutoff compare domain: k >> 12
#define HB 4096         // LDS histogram buckets
#define HBASE 0x40800   // (k>>12) of the highest valid score (~1.0); valid span = 4096
#define IDX_PAD 0xFFFFFFFFu

__device__ __forceinline__ unsigned key_of(float s) {
    // monotone map: larger score -> SMALLER key (ascending sort = descending score)
    unsigned u = __float_as_uint(s);
    unsigned m = (u & 0x80000000u) ? ~u : (u | 0x80000000u);
    return ~m;
}

// ---------------- kernel 1: per-box max-product score -> k32 (PURE STREAM, no atomics) ----------------
__global__ __launch_bounds__(256, 2) void score_kernel(const float* __restrict__ x,
                                                       unsigned* __restrict__ k32) {
    int gid = blockIdx.x * 256 + threadIdx.x;
    int box = gid >> 1;
    int q = gid & 1;
    size_t base = (size_t)box * NCH;

    float obj = x[base + 4];
    const float4* p = (const float4*)(x + base + 5 + q * 40);
    float4 r[10];
    #pragma unroll
    for (int j = 0; j < 10; j++) r[j] = p[j];   // 10 independent loads in flight

    float v = -1e30f;
    #pragma unroll
    for (int j = 0; j < 10; j++) {              // max of products; value order-invariant
        float m0 = fmaxf(r[j].x * obj, r[j].y * obj);
        float m1 = fmaxf(r[j].z * obj, r[j].w * obj);
        v = fmaxf(v, fmaxf(m0, m1));
    }
    v = fmaxf(v, __shfl_xor(v, 1));             // combine halves

    if (q == 0) {
        bool validb = (obj > 0.25f) && (v > 0.25f);
        float score = validb ? v : -1.0f;
        k32[box] = key_of(score);
    }
}

// ---------------- kernel 2: LDS histogram + cutoff covering rank KPRE (1 block / batch) ----------------
// Valid keys (score in (0.25,1)) have k>>12 in [HBASE, HBASE+4096): exact 4096-bucket LDS hist.
__global__ __launch_bounds__(1024) void select_cutoff(const unsigned* __restrict__ k32,
                                                      unsigned* __restrict__ cutoff) {
    __shared__ unsigned h[HB];                   // 16 KB
    __shared__ unsigned part[1024];
    __shared__ unsigned wsum[16];
    int b = blockIdx.x, t = threadIdx.x;
    int lane = t & 63, wv = t >> 6;

    #pragma unroll
    for (int j = 0; j < HB / 1024; j++) h[t + j * 1024] = 0;
    __syncthreads();

    const unsigned* kb = k32 + (size_t)b * NBOX;
    for (int i = t; i < NBOX; i += 1024) {
        unsigned k = kb[i];
        if ((int)k >= 0) {                       // valid (sign bit clear)
            int bu = (int)(k >> CSHIFT) - HBASE;
            bu = bu < 0 ? 0 : (bu > HB - 1 ? HB - 1 : bu);
            atomicAdd(&h[bu], 1u);               // LDS atomic, ~4.6 entries/bucket
        }
    }
    __syncthreads();

    unsigned s = h[4 * t] + h[4 * t + 1] + h[4 * t + 2] + h[4 * t + 3];
    part[t] = s;
    unsigned ws = s;
    #pragma unroll
    for (int off = 1; off < 64; off <<= 1) ws += __shfl_xor(ws, off);
    if (lane == 0) wsum[wv] = ws;
    __syncthreads();
    if (t == 0) {
        unsigned cum = 0; int W = -1;
        for (int w = 0; w < 16; w++)
            if (W < 0) { if (cum + wsum[w] >= KPRE) W = w; else cum += wsum[w]; }
        int T = -1;
        if (W >= 0)
            for (int i = 0; i < 64; i++)
                if (T < 0) { int p = W * 64 + i; if (cum + part[p] >= KPRE) T = p; else cum += part[p]; }
        unsigned P = HB - 1;                     // fewer than KPRE valid -> take all valid
        if (T >= 0)
            for (int j = 0; j < 4; j++) { cum += h[T * 4 + j]; if (cum >= KPRE) { P = (unsigned)(T * 4 + j); break; } }
        cutoff[b] = P + HBASE;                   // compare domain: (k >> CSHIFT) <= cutoff
    }
}

// ---------------- kernel 3: fused compaction + bitonic sort + decode (1 block / batch) ----------------
__global__ __launch_bounds__(1024) void sort_gather(const unsigned* __restrict__ k32,
                                                    const unsigned* __restrict__ cutoff,
                                                    float* __restrict__ topconf,
                                                    unsigned* __restrict__ topidx) {
    __shared__ unsigned long long keys[NCAND_MAX];   // 32 KB
    __shared__ unsigned cnt[25][16];
    __shared__ unsigned waveOff[25][16];
    __shared__ unsigned chunkBase[25];
    __shared__ unsigned totc[25];
    __shared__ unsigned nTot;
    int b = blockIdx.x, t = threadIdx.x;
    int lane = t & 63, wv = t >> 6;
    unsigned P = cutoff[b];
    const unsigned* kb = k32 + (size_t)b * NBOX;

    // ---- compaction: 25 chunks of 1024, all loads in flight, ballot count matrix ----
    unsigned kreg[25];
    unsigned passbits = 0;
    #pragma unroll
    for (int c = 0; c < 25; c++) {
        int i = c * 1024 + t;
        unsigned k = 0; bool p = false;
        if (i < NBOX) { k = kb[i]; p = ((int)k >= 0) && ((k >> CSHIFT) <= P); }
        kreg[c] = k;
        passbits |= (p ? 1u : 0u) << c;
    }
    #pragma unroll
    for (int c = 0; c < 25; c++) {
        unsigned long long m = __ballot((passbits >> c) & 1u);
        if (lane == 0) cnt[c][wv] = (unsigned)__popcll(m);
    }
    __syncthreads();
    if (t < 25) {
        unsigned run = 0;
        #pragma unroll
        for (int w2 = 0; w2 < 16; w2++) { waveOff[t][w2] = run; run += cnt[t][w2]; }
        totc[t] = run;
    }
    __syncthreads();
    if (t == 0) {
        unsigned acc = 0;
        for (int c = 0; c < 25; c++) { chunkBase[c] = acc; acc += totc[c]; }
        nTot = acc;
    }
    __syncthreads();
    int n = (int)nTot; if (n > NCAND_MAX) n = NCAND_MAX;
    #pragma unroll
    for (int c = 0; c < 25; c++) {
        unsigned long long m = __ballot((passbits >> c) & 1u);
        if ((passbits >> c) & 1u) {
            unsigned rank = chunkBase[c] + waveOff[c][wv] +
                            (unsigned)__popcll(lane ? (m & ((~0ull) >> (64 - lane))) : 0ull);
            if (rank < NCAND_MAX)
                keys[rank] = ((unsigned long long)kreg[c] << 32) | (unsigned)(c * 1024 + t);
        }
    }
    int m2 = KPRE;
    while (m2 < n) m2 <<= 1;
    int nq = m2 >> 10;
    for (int q = 0; q < nq; q++) { int s2 = t + (q << 10); if (s2 >= n) keys[s2] = ~0ull; }
    __syncthreads();

    // ---- ascending bitonic sort: key ascending = score descending, ties by ascending idx ----
    for (int k = 2; k <= m2; k <<= 1) {
        for (int j = k >> 1; j > 0; j >>= 1) {
            for (int q = 0; q < nq; q++) {
                int i = t + (q << 10);
                int ixj = i ^ j;
                if (ixj > i) {
                    unsigned long long a = keys[i], bb = keys[ixj];
                    bool up = ((i & k) == 0);
                    if ((a > bb) == up) { keys[i] = bb; keys[ixj] = a; }
                }
            }
            __syncthreads();
        }
    }

    // ---- decode rank t ----
    int o = (b << 10) + t;
    if (t < n) {
        unsigned long long key = keys[t];
        unsigned kk = (unsigned)(key >> 32);
        unsigned mm = ~kk;
        unsigned bits = (mm & 0x80000000u) ? (mm & 0x7FFFFFFFu) : ~mm;
        topconf[o] = __uint_as_float(bits);     // exact original score
        topidx[o] = (unsigned)(key & 0xFFFFFFFFu);
    } else {
        topconf[o] = -1.0f;
        topidx[o] = IDX_PAD;
    }
}

// ---------------- kernel 4: exact argmax + box build for the 16K survivors only ----------------
__global__ __launch_bounds__(256) void argmax_gather(const float* __restrict__ x,
                                                     const unsigned* __restrict__ topidx,
                                                     float4* __restrict__ topbox,
                                                     float4* __restrict__ topoff,
                                                     float* __restrict__ topcls) {
#pragma clang fp contract(off)
    int gid = blockIdx.x * 256 + threadIdx.x;
    int o = gid >> 2;                           // entry in [0, BATCH*KPRE)
    int q = gid & 3;
    int b = o >> 10;
    unsigned idx = topidx[o];

    float4 box = make_float4(0.f, 0.f, 0.f, 0.f);
    float clsf = 0.f;
    if (idx != IDX_PAD) {
        size_t base = ((size_t)b * NBOX + idx) * NCH;
        float obj = x[base + 4];
        int cbase = 5 + q * 20;
        float v = -1e30f; int c = 0;
        #pragma unroll
        for (int j = 0; j < 20; j++) {
            float s = x[base + cbase + j] * obj;
            if (s > v) { v = s; c = q * 20 + j; }      // strict > = first occurrence
        }
        #pragma unroll
        for (int off = 1; off <= 2; off <<= 1) {
            float ov = __shfl_xor(v, off);
            int   oc = __shfl_xor(c, off);
            if (ov > v || (ov == v && oc < c)) { v = ov; c = oc; }
        }
        if (q == 0) {
            float cx = x[base + 0], cy = x[base + 1], w = x[base + 2], h = x[base + 3];
            box = make_float4(cx - w * 0.5f, cy - h * 0.5f, cx + w * 0.5f, cy + h * 0.5f);
            clsf = (float)c;
        }
    }
    if (q == 0) {
        topbox[o] = box;
        topcls[o] = clsf;
        float off = clsf * 4096.0f;
        topoff[o] = make_float4(box.x + off, box.y + off, box.z + off, box.w + off);
    }
}

// ---------------- kernel 5: pairwise IoU bitmask, TRANSPOSED LDS (conflict-free) ----------------
__global__ __launch_bounds__(256) void iou_mask(const float4* __restrict__ topoff,
                                                unsigned long long* __restrict__ mask,
                                                unsigned short* __restrict__ summ) {
#pragma clang fp contract(off)
    __shared__ float4 soff[KPRE];
    int b = blockIdx.x >> 6;
    int blk = blockIdx.x & 63;
    int t = threadIdx.x;
    // contiguous LDS slots (no write conflict); permuted global read still 16 lines/instr
    for (int q = 0; q < 4; q++) {
        int u = t + q * 256;                       // LDS slot
        int s = ((u & 15) << 6) | (u >> 4);        // source box = invperm(u)
        soff[u] = topoff[(b << 10) + s];
    }
    __syncthreads();
    int i = (blk << 4) + (t >> 4);
    int w = t & 15;
    unsigned long long bits = 0;
    int jbase = w << 6;
    if (jbase + 63 > i) {                          // lower-triangle words are identically 0
        float4 a = soff[((i & 63) << 4) | (i >> 6)];
        float area_a = (a.z - a.x) * (a.w - a.y);
        for (int jj = 0; jj < 64; jj++) {
            int j = jbase + jj;
            float4 bb = soff[(jj << 4) | w];       // transposed slot for box j
            float area_b = (bb.z - bb.x) * (bb.w - bb.y);
            float ltx = fmaxf(a.x, bb.x), lty = fmaxf(a.y, bb.y);
            float rbx = fminf(a.z, bb.z), rby = fminf(a.w, bb.w);
            float wx = fmaxf(rbx - ltx, 0.0f), wy = fmaxf(rby - lty, 0.0f);
            float inter = wx * wy;
            float iou = inter / (area_a + area_b - inter + 1e-7f);
            if (j > i && iou > 0.45f) bits |= (1ull << jj);
        }
    }
    mask[((size_t)((b << 10) + i) << 4) + w] = bits;
    unsigned long long bal = __ballot(bits != 0ull);
    if (w == 0) {
        int l = t & 63;
        summ[(b << 10) + i] = (unsigned short)((bal >> ((l >> 4) << 4)) & 0xFFFFull);
    }
}

// ---------------- kernel 6: greedy suppression + ordered output (1 block / batch) ----------------
__global__ __launch_bounds__(1024) void nms_finalize(const unsigned long long* __restrict__ mask,
                                                     const unsigned short* __restrict__ summ,
                                                     const float* __restrict__ topconf,
                                                     const float4* __restrict__ topbox,
                                                     const float* __restrict__ topcls,
                                                     float* __restrict__ dets,
                                                     float* __restrict__ vmask) {
    __shared__ unsigned long long kb[16];
    int b = blockIdx.x, tid = threadIdx.x;

    if (tid < 64) {
        int lane = tid;
        const unsigned long long* mrow = mask + ((size_t)b << 14);
        unsigned long long keep0[16];
        #pragma unroll
        for (int c = 0; c < 16; c++) {
            float cf = topconf[(b << 10) + (c << 6) + lane];
            keep0[c] = __ballot(cf > 0.0f);
        }
        unsigned nz[16];
        #pragma unroll
        for (int t = 0; t < 16; t++)
            nz[t] = (unsigned)summ[(b << 10) + (t << 6) + lane];
        unsigned long long diag[16];
        #pragma unroll
        for (int t = 0; t < 16; t++)
            diag[t] = mrow[((size_t)((t << 6) + lane) << 4) + t];

        unsigned long long remv[16];
        #pragma unroll
        for (int t = 0; t < 16; t++) remv[t] = 0;

        #pragma unroll
        for (int t = 0; t < 16; t++) {
            unsigned long long live = keep0[t] & ~remv[t];
            unsigned long long kept = live;
            unsigned long long pend = live & __ballot((nz[t] >> t) & 1u);
            while (pend) {
                int j = (int)__ffsll(pend) - 1;
                pend &= pend - 1;
                if ((kept >> j) & 1ull) {
                    unsigned long long dj = __shfl(diag[t], j);
                    kept &= ~dj;
                    pend &= ~dj;
                }
            }
            if (lane == 0) kb[t] = kept;

            #pragma unroll
            for (int w = 0; w < 16; w++) {
                if (w > t) {
                    unsigned long long wm = kept & __ballot((nz[t] >> w) & 1u);
                    while (wm) {
                        int j = (int)__ffsll(wm) - 1;
                        wm &= wm - 1;
                        remv[w] |= mrow[((size_t)((t << 6) + j) << 4) + w];
                    }
                }
            }
        }
    }
    __syncthreads();

    int r = tid;
    int w = r >> 6, l = r & 63;
    unsigned long long word = kb[w];
    int keep = (int)((word >> l) & 1ull);
    int base = 0, total = 0;
    #pragma unroll
    for (int q = 0; q < 16; q++) {
        int c = __popcll(kb[q]);
        total += c;
        if (q < w) base += c;
    }
    int rank = base + __popcll((l == 0) ? 0ull : (word & ((~0ull) >> (64 - l))));
    float* drow = dets + (size_t)b * (MAXDET * 6);
    float* vm = vmask + (size_t)b * MAXDET;
    if (r < MAXDET && r >= total) {
#pragma unroll
        for (int cc = 0; cc < 6; cc++) drow[r * 6 + cc] = 0.0f;
        vm[r] = 0.0f;
    }
    if (keep && rank < MAXDET) {
        int o = (b << 10) + r;
        float4 bx = topbox[o];
        drow[rank * 6 + 0] = bx.x;
        drow[rank * 6 + 1] = bx.y;
        drow[rank * 6 + 2] = bx.z;
        drow[rank * 6 + 3] = bx.w;
        drow[rank * 6 + 4] = topconf[o];
        drow[rank * 6 + 5] = topcls[o];
        vm[rank] = 1.0f;
    }
}

// ---------------- launcher ----------------
extern "C" void kernel_launch(void* const* d_in, const int* in_sizes, int n_in,
                              void* d_out, int out_size, void* d_ws, size_t ws_size,
                              hipStream_t stream) {
    const float* x = (const float*)d_in[0];
    char* w = (char*)d_ws;

    // workspace layout (bytes), total 4,463,808
    unsigned long long* mask    = (unsigned long long*)(w + 0);        // 2,097,152
    unsigned*           k32     = (unsigned*)(w + 2097152);            // 1,612,800
    float4*             topbox  = (float4*)(w + 3709952);              // 262,144
    float4*             topoff  = (float4*)(w + 3972096);              // 262,144
    float*              topconf = (float*)(w + 4234240);               // 65,536
    float*              topcls  = (float*)(w + 4299776);               // 65,536
    unsigned*           topidx  = (unsigned*)(w + 4365312);            // 65,536
    unsigned*           cutoff  = (unsigned*)(w + 4430848);            // 64
    unsigned short*     summ    = (unsigned short*)(w + 4430912);      // 32,768
    if (ws_size < 4463808) return;  // insufficient scratch -> deterministic failure

    score_kernel<<<(BATCH * NBOX * 2) / 256, 256, 0, stream>>>(x, k32);
    select_cutoff<<<BATCH, 1024, 0, stream>>>(k32, cutoff);
    sort_gather<<<BATCH, 1024, 0, stream>>>(k32, cutoff, topconf, topidx);
    argmax_gather<<<(BATCH * KPRE * 4) / 256, 256, 0, stream>>>(x, topidx, topbox, topoff, topcls);
    iou_mask<<<BATCH * 64, 256, 0, stream>>>(topoff, mask, summ);

    float* dets = (float*)d_out;
    float* vmask = dets + (size_t)BATCH * MAXDET * 6;
    nms_finalize<<<BATCH, 1024, 0, stream>>>(mask, summ, topconf, topbox, topcls, dets, vmask);
}

// Round 17
// 104.371 us; speedup vs baseline: 1.9315x; 1.0668x over previous
//
#include <hip/hip_runtime.h>
#include <cstdint>
#include <cstddef>

// ---------------- problem constants ----------------
#define BATCH 16
#define NBOX 25200
#define NCH 85          // 4 box + 1 obj + 80 cls
#define KPRE 1024
#define MAXDET 1000
#define NCAND_MAX 4096
#define CSHIFT 12       // cutoff compare domain: k >> 12
#define HB 4096         // LDS histogram buckets
#define HBASE 0x40800   // (k>>12) of the highest valid score (~1.0); valid span = 4096
#define IDX_PAD 0xFFFFFFFFu

__device__ __forceinline__ unsigned key_of(float s) {
    // monotone map: larger score -> SMALLER key (ascending sort = descending score)
    unsigned u = __float_as_uint(s);
    unsigned m = (u & 0x80000000u) ? ~u : (u | 0x80000000u);
    return ~m;
}

// ---------------- kernel 1: per-box max score, 4-lane line-contiguous, NO atomics ----------------
// Lane q of a box loads float4 chunks q,q+4,..,q+16: each 4-lane group's 64B is one full
// cache line consumed per instruction -> no L1-retention dependence, pure stream.
__global__ __launch_bounds__(256) void score_kernel(const float* __restrict__ x,
                                                    unsigned* __restrict__ k32) {
    int gid = blockIdx.x * 256 + threadIdx.x;
    int box = gid >> 2;
    int q = gid & 3;
    const float* rowp = x + (size_t)box * NCH;

    float obj = rowp[4];                              // broadcast within group (1 line)
    const float4* p4 = (const float4*)rowp;           // 4B-aligned vector loads (valid on gfx950)
    float4 r0 = p4[q];                                // chunks 0..19 = floats 0..79
    float4 r1 = p4[q + 4];
    float4 r2 = p4[q + 8];
    float4 r3 = p4[q + 12];
    float4 r4 = p4[q + 16];
    float4 rt = p4[20];                               // floats 80..83 (cls 75..78), broadcast
    float c79 = rowp[84];                             // cls 79, broadcast

    // mask non-class floats: q==0 chunk0 = box coords; q==1 chunk1.x = obj
    if (q == 0) { r0.x = -1e30f; r0.y = -1e30f; r0.z = -1e30f; r0.w = -1e30f; }
    if (q == 1) { r0.x = -1e30f; }

    float v = fmaxf(fmaxf(r0.x, r0.y), fmaxf(r0.z, r0.w));
    v = fmaxf(v, fmaxf(fmaxf(r1.x, r1.y), fmaxf(r1.z, r1.w)));
    v = fmaxf(v, fmaxf(fmaxf(r2.x, r2.y), fmaxf(r2.z, r2.w)));
    v = fmaxf(v, fmaxf(fmaxf(r3.x, r3.y), fmaxf(r3.z, r3.w)));
    v = fmaxf(v, fmaxf(fmaxf(r4.x, r4.y), fmaxf(r4.z, r4.w)));
    v = fmaxf(v, fmaxf(fmaxf(rt.x, rt.y), fmaxf(rt.z, rt.w)));
    v = fmaxf(v, c79);
    v = fmaxf(v, __shfl_xor(v, 1));
    v = fmaxf(v, __shfl_xor(v, 2));                   // max(cls) across the 4 lanes

    if (q == 0) {
        float conf = obj * v;                         // = max(cls*obj) exactly (monotone mul, obj>=0)
        bool validb = (obj > 0.25f) && (conf > 0.25f);
        k32[box] = key_of(validb ? conf : -1.0f);
    }
}

// ---------------- kernel 2: fused hist+cutoff + compaction + bitonic sort + decode ----------------
// 1 block / batch. All 25200 keys land in registers ONCE; LDS hist is built from registers,
// cutoff scanned in-kernel, then the proven 4-barrier compaction + bitonic + decode.
__global__ __launch_bounds__(1024) void sort_gather(const unsigned* __restrict__ k32,
                                                    float* __restrict__ topconf,
                                                    unsigned* __restrict__ topidx) {
    __shared__ unsigned long long keys[NCAND_MAX];   // 32 KB
    __shared__ unsigned h[HB];                       // 16 KB
    __shared__ unsigned part[1024];
    __shared__ unsigned wsum[16];
    __shared__ unsigned cnt[25][16];
    __shared__ unsigned waveOff[25][16];
    __shared__ unsigned chunkBase[25];
    __shared__ unsigned totc[25];
    __shared__ unsigned cutP, nTot;
    int b = blockIdx.x, t = threadIdx.x;
    int lane = t & 63, wv = t >> 6;
    const unsigned* kb = k32 + (size_t)b * NBOX;

    // ---- load all keys into registers (25 coalesced loads in flight) ----
    unsigned kreg[25];
    unsigned validbits = 0;
    #pragma unroll
    for (int c = 0; c < 25; c++) {
        int i = c * 1024 + t;
        unsigned k = 0x80000000u;                    // invalid sentinel for tail
        if (i < NBOX) k = kb[i];
        kreg[c] = k;
        validbits |= (((int)k >= 0) ? 1u : 0u) << c;
    }

    // ---- LDS histogram over valid keys ----
    #pragma unroll
    for (int j = 0; j < HB / 1024; j++) h[t + j * 1024] = 0;
    __syncthreads();
    #pragma unroll
    for (int c = 0; c < 25; c++) {
        if ((validbits >> c) & 1u) {
            int bu = (int)(kreg[c] >> CSHIFT) - HBASE;
            bu = bu < 0 ? 0 : (bu > HB - 1 ? HB - 1 : bu);
            atomicAdd(&h[bu], 1u);                   // LDS atomic, ~4.6 entries/bucket
        }
    }
    __syncthreads();

    // ---- cutoff covering rank KPRE ----
    {
        unsigned s = h[4 * t] + h[4 * t + 1] + h[4 * t + 2] + h[4 * t + 3];
        part[t] = s;
        unsigned ws = s;
        #pragma unroll
        for (int off = 1; off < 64; off <<= 1) ws += __shfl_xor(ws, off);
        if (lane == 0) wsum[wv] = ws;
    }
    __syncthreads();
    if (t == 0) {
        unsigned cum = 0; int W = -1;
        for (int w = 0; w < 16; w++)
            if (W < 0) { if (cum + wsum[w] >= KPRE) W = w; else cum += wsum[w]; }
        int T = -1;
        if (W >= 0)
            for (int i = 0; i < 64; i++)
                if (T < 0) { int p = W * 64 + i; if (cum + part[p] >= KPRE) T = p; else cum += part[p]; }
        unsigned P = HB - 1;                         // fewer than KPRE valid -> take all valid
        if (T >= 0)
            for (int j = 0; j < 4; j++) { cum += h[T * 4 + j]; if (cum >= KPRE) { P = (unsigned)(T * 4 + j); break; } }
        cutP = P + HBASE;                            // compare domain: (k >> CSHIFT) <= cutP
    }
    __syncthreads();
    unsigned P = cutP;

    // ---- deterministic index-ordered compaction (ballot count matrix, 4 barriers) ----
    unsigned passbits = 0;
    #pragma unroll
    for (int c = 0; c < 25; c++) {
        bool p = ((validbits >> c) & 1u) && ((kreg[c] >> CSHIFT) <= P);
        passbits |= (p ? 1u : 0u) << c;
    }
    #pragma unroll
    for (int c = 0; c < 25; c++) {
        unsigned long long m = __ballot((passbits >> c) & 1u);
        if (lane == 0) cnt[c][wv] = (unsigned)__popcll(m);
    }
    __syncthreads();
    if (t < 25) {
        unsigned run = 0;
        #pragma unroll
        for (int w2 = 0; w2 < 16; w2++) { waveOff[t][w2] = run; run += cnt[t][w2]; }
        totc[t] = run;
    }
    __syncthreads();
    if (t == 0) {
        unsigned acc = 0;
        for (int c = 0; c < 25; c++) { chunkBase[c] = acc; acc += totc[c]; }
        nTot = acc;
    }
    __syncthreads();
    int n = (int)nTot; if (n > NCAND_MAX) n = NCAND_MAX;
    #pragma unroll
    for (int c = 0; c < 25; c++) {
        unsigned long long m = __ballot((passbits >> c) & 1u);
        if ((passbits >> c) & 1u) {
            unsigned rank = chunkBase[c] + waveOff[c][wv] +
                            (unsigned)__popcll(lane ? (m & ((~0ull) >> (64 - lane))) : 0ull);
            if (rank < NCAND_MAX)
                keys[rank] = ((unsigned long long)kreg[c] << 32) | (unsigned)(c * 1024 + t);
        }
    }
    int m2 = KPRE;
    while (m2 < n) m2 <<= 1;
    int nq = m2 >> 10;
    for (int q = 0; q < nq; q++) { int s2 = t + (q << 10); if (s2 >= n) keys[s2] = ~0ull; }
    __syncthreads();

    // ---- ascending bitonic sort: key ascending = score descending, ties by ascending idx ----
    for (int k = 2; k <= m2; k <<= 1) {
        for (int j = k >> 1; j > 0; j >>= 1) {
            for (int q = 0; q < nq; q++) {
                int i = t + (q << 10);
                int ixj = i ^ j;
                if (ixj > i) {
                    unsigned long long a = keys[i], bb = keys[ixj];
                    bool up = ((i & k) == 0);
                    if ((a > bb) == up) { keys[i] = bb; keys[ixj] = a; }
                }
            }
            __syncthreads();
        }
    }

    // ---- decode rank t ----
    int o = (b << 10) + t;
    if (t < n) {
        unsigned long long key = keys[t];
        unsigned kk = (unsigned)(key >> 32);
        unsigned mm = ~kk;
        unsigned bits = (mm & 0x80000000u) ? (mm & 0x7FFFFFFFu) : ~mm;
        topconf[o] = __uint_as_float(bits);     // exact original score
        topidx[o] = (unsigned)(key & 0xFFFFFFFFu);
    } else {
        topconf[o] = -1.0f;
        topidx[o] = IDX_PAD;
    }
}

// ---------------- kernel 3: exact argmax + box build for the 16K survivors only ----------------
__global__ __launch_bounds__(256) void argmax_gather(const float* __restrict__ x,
                                                     const unsigned* __restrict__ topidx,
                                                     float4* __restrict__ topbox,
                                                     float4* __restrict__ topoff,
                                                     float* __restrict__ topcls) {
#pragma clang fp contract(off)
    int gid = blockIdx.x * 256 + threadIdx.x;
    int o = gid >> 2;                           // entry in [0, BATCH*KPRE)
    int q = gid & 3;
    int b = o >> 10;
    unsigned idx = topidx[o];

    float4 box = make_float4(0.f, 0.f, 0.f, 0.f);
    float clsf = 0.f;
    if (idx != IDX_PAD) {
        size_t base = ((size_t)b * NBOX + idx) * NCH;
        float obj = x[base + 4];
        int cbase = 5 + q * 20;
        float v = -1e30f; int c = 0;
        #pragma unroll
        for (int j = 0; j < 20; j++) {
            float s = x[base + cbase + j] * obj;
            if (s > v) { v = s; c = q * 20 + j; }      // strict > = first occurrence
        }
        #pragma unroll
        for (int off = 1; off <= 2; off <<= 1) {
            float ov = __shfl_xor(v, off);
            int   oc = __shfl_xor(c, off);
            if (ov > v || (ov == v && oc < c)) { v = ov; c = oc; }
        }
        if (q == 0) {
            float cx = x[base + 0], cy = x[base + 1], w = x[base + 2], h = x[base + 3];
            box = make_float4(cx - w * 0.5f, cy - h * 0.5f, cx + w * 0.5f, cy + h * 0.5f);
            clsf = (float)c;
        }
    }
    if (q == 0) {
        topbox[o] = box;
        topcls[o] = clsf;
        float off = clsf * 4096.0f;
        topoff[o] = make_float4(box.x + off, box.y + off, box.z + off, box.w + off);
    }
}

// ---------------- kernel 4: pairwise IoU bitmask, TRANSPOSED LDS (conflict-free) ----------------
__global__ __launch_bounds__(256) void iou_mask(const float4* __restrict__ topoff,
                                                unsigned long long* __restrict__ mask,
                                                unsigned short* __restrict__ summ) {
#pragma clang fp contract(off)
    __shared__ float4 soff[KPRE];
    int b = blockIdx.x >> 6;
    int blk = blockIdx.x & 63;
    int t = threadIdx.x;
    // contiguous LDS slots (no write conflict); permuted global read still 16 lines/instr
    for (int q = 0; q < 4; q++) {
        int u = t + q * 256;                       // LDS slot
        int s = ((u & 15) << 6) | (u >> 4);        // source box = invperm(u)
        soff[u] = topoff[(b << 10) + s];
    }
    __syncthreads();
    int i = (blk << 4) + (t >> 4);
    int w = t & 15;
    unsigned long long bits = 0;
    int jbase = w << 6;
    if (jbase + 63 > i) {                          // lower-triangle words are identically 0
        float4 a = soff[((i & 63) << 4) | (i >> 6)];
        float area_a = (a.z - a.x) * (a.w - a.y);
        for (int jj = 0; jj < 64; jj++) {
            int j = jbase + jj;
            float4 bb = soff[(jj << 4) | w];       // transposed slot for box j
            float area_b = (bb.z - bb.x) * (bb.w - bb.y);
            float ltx = fmaxf(a.x, bb.x), lty = fmaxf(a.y, bb.y);
            float rbx = fminf(a.z, bb.z), rby = fminf(a.w, bb.w);
            float wx = fmaxf(rbx - ltx, 0.0f), wy = fmaxf(rby - lty, 0.0f);
            float inter = wx * wy;
            float iou = inter / (area_a + area_b - inter + 1e-7f);
            if (j > i && iou > 0.45f) bits |= (1ull << jj);
        }
    }
    mask[((size_t)((b << 10) + i) << 4) + w] = bits;
    unsigned long long bal = __ballot(bits != 0ull);
    if (w == 0) {
        int l = t & 63;
        summ[(b << 10) + i] = (unsigned short)((bal >> ((l >> 4) << 4)) & 0xFFFFull);
    }
}

// ---------------- kernel 5: greedy suppression + ordered output (1 block / batch) ----------------
__global__ __launch_bounds__(1024) void nms_finalize(const unsigned long long* __restrict__ mask,
                                                     const unsigned short* __restrict__ summ,
                                                     const float* __restrict__ topconf,
                                                     const float4* __restrict__ topbox,
                                                     const float* __restrict__ topcls,
                                                     float* __restrict__ dets,
                                                     float* __restrict__ vmask) {
    __shared__ unsigned long long kb[16];
    int b = blockIdx.x, tid = threadIdx.x;

    if (tid < 64) {
        int lane = tid;
        const unsigned long long* mrow = mask + ((size_t)b << 14);
        unsigned long long keep0[16];
        #pragma unroll
        for (int c = 0; c < 16; c++) {
            float cf = topconf[(b << 10) + (c << 6) + lane];
            keep0[c] = __ballot(cf > 0.0f);
        }
        unsigned nz[16];
        #pragma unroll
        for (int t = 0; t < 16; t++)
            nz[t] = (unsigned)summ[(b << 10) + (t << 6) + lane];
        unsigned long long diag[16];
        #pragma unroll
        for (int t = 0; t < 16; t++)
            diag[t] = mrow[((size_t)((t << 6) + lane) << 4) + t];

        unsigned long long remv[16];
        #pragma unroll
        for (int t = 0; t < 16; t++) remv[t] = 0;

        #pragma unroll
        for (int t = 0; t < 16; t++) {
            unsigned long long live = keep0[t] & ~remv[t];
            unsigned long long kept = live;
            unsigned long long pend = live & __ballot((nz[t] >> t) & 1u);
            while (pend) {
                int j = (int)__ffsll(pend) - 1;
                pend &= pend - 1;
                if ((kept >> j) & 1ull) {
                    unsigned long long dj = __shfl(diag[t], j);
                    kept &= ~dj;
                    pend &= ~dj;
                }
            }
            if (lane == 0) kb[t] = kept;

            #pragma unroll
            for (int w = 0; w < 16; w++) {
                if (w > t) {
                    unsigned long long wm = kept & __ballot((nz[t] >> w) & 1u);
                    while (wm) {
                        int j = (int)__ffsll(wm) - 1;
                        wm &= wm - 1;
                        remv[w] |= mrow[((size_t)((t << 6) + j) << 4) + w];
                    }
                }
            }
        }
    }
    __syncthreads();

    int r = tid;
    int w = r >> 6, l = r & 63;
    unsigned long long word = kb[w];
    int keep = (int)((word >> l) & 1ull);
    int base = 0, total = 0;
    #pragma unroll
    for (int q = 0; q < 16; q++) {
        int c = __popcll(kb[q]);
        total += c;
        if (q < w) base += c;
    }
    int rank = base + __popcll((l == 0) ? 0ull : (word & ((~0ull) >> (64 - l))));
    float* drow = dets + (size_t)b * (MAXDET * 6);
    float* vm = vmask + (size_t)b * MAXDET;
    if (r < MAXDET && r >= total) {
#pragma unroll
        for (int cc = 0; cc < 6; cc++) drow[r * 6 + cc] = 0.0f;
        vm[r] = 0.0f;
    }
    if (keep && rank < MAXDET) {
        int o = (b << 10) + r;
        float4 bx = topbox[o];
        drow[rank * 6 + 0] = bx.x;
        drow[rank * 6 + 1] = bx.y;
        drow[rank * 6 + 2] = bx.z;
        drow[rank * 6 + 3] = bx.w;
        drow[rank * 6 + 4] = topconf[o];
        drow[rank * 6 + 5] = topcls[o];
        vm[rank] = 1.0f;
    }
}

// ---------------- launcher ----------------
extern "C" void kernel_launch(void* const* d_in, const int* in_sizes, int n_in,
                              void* d_out, int out_size, void* d_ws, size_t ws_size,
                              hipStream_t stream) {
    const float* x = (const float*)d_in[0];
    char* w = (char*)d_ws;

    // workspace layout (bytes), total 4,463,744
    unsigned long long* mask    = (unsigned long long*)(w + 0);        // 2,097,152
    unsigned*           k32     = (unsigned*)(w + 2097152);            // 1,612,800
    float4*             topbox  = (float4*)(w + 3709952);              // 262,144
    float4*             topoff  = (float4*)(w + 3972096);              // 262,144
    float*              topconf = (float*)(w + 4234240);               // 65,536
    float*              topcls  = (float*)(w + 4299776);               // 65,536
    unsigned*           topidx  = (unsigned*)(w + 4365312);            // 65,536
    unsigned short*     summ    = (unsigned short*)(w + 4430848);      // 32,768
    if (ws_size < 4463616) return;  // insufficient scratch -> deterministic failure

    score_kernel<<<(BATCH * NBOX * 4) / 256, 256, 0, stream>>>(x, k32);
    sort_gather<<<BATCH, 1024, 0, stream>>>(k32, topconf, topidx);
    argmax_gather<<<(BATCH * KPRE * 4) / 256, 256, 0, stream>>>(x, topidx, topbox, topoff, topcls);
    iou_mask<<<BATCH * 64, 256, 0, stream>>>(topoff, mask, summ);

    float* dets = (float*)d_out;
    float* vmask = dets + (size_t)BATCH * MAXDET * 6;
    nms_finalize<<<BATCH, 1024, 0, stream>>>(mask, summ, topconf, topbox, topcls, dets, vmask);
}

// Round 18
// 95.570 us; speedup vs baseline: 2.1094x; 1.0921x over previous
//
#include <hip/hip_runtime.h>
#include <cstdint>
#include <cstddef>

// ---------------- problem constants ----------------
#define BATCH 16
#define NBOX 25200
#define NCH 85          // 4 box + 1 obj + 80 cls
#define KPRE 1024
#define MAXDET 1000
#define NCAND_MAX 4096
#define CSHIFT 12       // cutoff compare domain: k >> 12
#define HB 4096         // LDS histogram buckets
#define HBASE 0x40800   // (k>>12) of the highest valid score (~1.0); valid span = 4096
#define IDX_PAD 0xFFFFFFFFu

__device__ __forceinline__ unsigned key_of(float s) {
    // monotone map: larger score -> SMALLER key (ascending sort = descending score)
    unsigned u = __float_as_uint(s);
    unsigned m = (u & 0x80000000u) ? ~u : (u | 0x80000000u);
    return ~m;
}

// ---------------- kernel 1: per-box max score, 4-lane line-contiguous, NO atomics ----------------
__global__ __launch_bounds__(256) void score_kernel(const float* __restrict__ x,
                                                    unsigned* __restrict__ k32) {
    int gid = blockIdx.x * 256 + threadIdx.x;
    int box = gid >> 2;
    int q = gid & 3;
    const float* rowp = x + (size_t)box * NCH;

    float obj = rowp[4];                              // broadcast within group (1 line)
    const float4* p4 = (const float4*)rowp;           // 4B-aligned vector loads (valid on gfx950)
    float4 r0 = p4[q];                                // chunks 0..19 = floats 0..79
    float4 r1 = p4[q + 4];
    float4 r2 = p4[q + 8];
    float4 r3 = p4[q + 12];
    float4 r4 = p4[q + 16];
    float4 rt = p4[20];                               // floats 80..83 (cls 75..78), broadcast
    float c79 = rowp[84];                             // cls 79, broadcast

    // mask non-class floats: q==0 chunk0 = box coords; q==1 chunk1.x = obj
    if (q == 0) { r0.x = -1e30f; r0.y = -1e30f; r0.z = -1e30f; r0.w = -1e30f; }
    if (q == 1) { r0.x = -1e30f; }

    float v = fmaxf(fmaxf(r0.x, r0.y), fmaxf(r0.z, r0.w));
    v = fmaxf(v, fmaxf(fmaxf(r1.x, r1.y), fmaxf(r1.z, r1.w)));
    v = fmaxf(v, fmaxf(fmaxf(r2.x, r2.y), fmaxf(r2.z, r2.w)));
    v = fmaxf(v, fmaxf(fmaxf(r3.x, r3.y), fmaxf(r3.z, r3.w)));
    v = fmaxf(v, fmaxf(fmaxf(r4.x, r4.y), fmaxf(r4.z, r4.w)));
    v = fmaxf(v, fmaxf(fmaxf(rt.x, rt.y), fmaxf(rt.z, rt.w)));
    v = fmaxf(v, c79);
    v = fmaxf(v, __shfl_xor(v, 1));
    v = fmaxf(v, __shfl_xor(v, 2));                   // max(cls) across the 4 lanes

    if (q == 0) {
        float conf = obj * v;                         // = max(cls*obj) exactly (monotone mul, obj>=0)
        bool validb = (obj > 0.25f) && (conf > 0.25f);
        k32[box] = key_of(validb ? conf : -1.0f);
    }
}

// ---------------- kernel 2: fused hist+cutoff + compaction + bitonic sort + decode ----------------
// Sort: levels k<=64 and all j<=32 passes run in REGISTERS via shfl_xor (partner i^j is
// in-wave for j<64) -> 51 of 66 passes barrier-free; only j>=64 passes touch LDS.
__global__ __launch_bounds__(1024) void sort_gather(const unsigned* __restrict__ k32,
                                                    float* __restrict__ topconf,
                                                    unsigned* __restrict__ topidx) {
    __shared__ unsigned long long keys[NCAND_MAX];   // 32 KB
    __shared__ unsigned h[HB];                       // 16 KB
    __shared__ unsigned part[1024];
    __shared__ unsigned wsum[16];
    __shared__ unsigned cnt[25][16];
    __shared__ unsigned waveOff[25][16];
    __shared__ unsigned chunkBase[25];
    __shared__ unsigned totc[25];
    __shared__ unsigned cutP, nTot;
    int b = blockIdx.x, t = threadIdx.x;
    int lane = t & 63, wv = t >> 6;
    const unsigned* kb = k32 + (size_t)b * NBOX;

    // ---- load all keys into registers (25 coalesced loads in flight) ----
    unsigned kreg[25];
    unsigned validbits = 0;
    #pragma unroll
    for (int c = 0; c < 25; c++) {
        int i = c * 1024 + t;
        unsigned k = 0x80000000u;                    // invalid sentinel for tail
        if (i < NBOX) k = kb[i];
        kreg[c] = k;
        validbits |= (((int)k >= 0) ? 1u : 0u) << c;
    }

    // ---- LDS histogram over valid keys ----
    #pragma unroll
    for (int j = 0; j < HB / 1024; j++) h[t + j * 1024] = 0;
    __syncthreads();
    #pragma unroll
    for (int c = 0; c < 25; c++) {
        if ((validbits >> c) & 1u) {
            int bu = (int)(kreg[c] >> CSHIFT) - HBASE;
            bu = bu < 0 ? 0 : (bu > HB - 1 ? HB - 1 : bu);
            atomicAdd(&h[bu], 1u);                   // LDS atomic, ~4.6 entries/bucket
        }
    }
    __syncthreads();

    // ---- cutoff covering rank KPRE ----
    {
        unsigned s = h[4 * t] + h[4 * t + 1] + h[4 * t + 2] + h[4 * t + 3];
        part[t] = s;
        unsigned ws = s;
        #pragma unroll
        for (int off = 1; off < 64; off <<= 1) ws += __shfl_xor(ws, off);
        if (lane == 0) wsum[wv] = ws;
    }
    __syncthreads();
    if (t == 0) {
        unsigned cum = 0; int W = -1;
        for (int w = 0; w < 16; w++)
            if (W < 0) { if (cum + wsum[w] >= KPRE) W = w; else cum += wsum[w]; }
        int T = -1;
        if (W >= 0)
            for (int i = 0; i < 64; i++)
                if (T < 0) { int p = W * 64 + i; if (cum + part[p] >= KPRE) T = p; else cum += part[p]; }
        unsigned P = HB - 1;                         // fewer than KPRE valid -> take all valid
        if (T >= 0)
            for (int j = 0; j < 4; j++) { cum += h[T * 4 + j]; if (cum >= KPRE) { P = (unsigned)(T * 4 + j); break; } }
        cutP = P + HBASE;                            // compare domain: (k >> CSHIFT) <= cutP
    }
    __syncthreads();
    unsigned P = cutP;

    // ---- deterministic index-ordered compaction (ballot count matrix) ----
    unsigned passbits = 0;
    #pragma unroll
    for (int c = 0; c < 25; c++) {
        bool p = ((validbits >> c) & 1u) && ((kreg[c] >> CSHIFT) <= P);
        passbits |= (p ? 1u : 0u) << c;
    }
    #pragma unroll
    for (int c = 0; c < 25; c++) {
        unsigned long long m = __ballot((passbits >> c) & 1u);
        if (lane == 0) cnt[c][wv] = (unsigned)__popcll(m);
    }
    __syncthreads();
    if (t < 25) {
        unsigned run = 0;
        #pragma unroll
        for (int w2 = 0; w2 < 16; w2++) { waveOff[t][w2] = run; run += cnt[t][w2]; }
        totc[t] = run;
    }
    __syncthreads();
    if (t == 0) {
        unsigned acc = 0;
        for (int c = 0; c < 25; c++) { chunkBase[c] = acc; acc += totc[c]; }
        nTot = acc;
    }
    __syncthreads();
    int n = (int)nTot; if (n > NCAND_MAX) n = NCAND_MAX;
    #pragma unroll
    for (int c = 0; c < 25; c++) {
        unsigned long long m = __ballot((passbits >> c) & 1u);
        if ((passbits >> c) & 1u) {
            unsigned rank = chunkBase[c] + waveOff[c][wv] +
                            (unsigned)__popcll(lane ? (m & ((~0ull) >> (64 - lane))) : 0ull);
            if (rank < NCAND_MAX)
                keys[rank] = ((unsigned long long)kreg[c] << 32) | (unsigned)(c * 1024 + t);
        }
    }
    int m2 = 2048;                                   // fast path always sorts 2048
    while (m2 < n) m2 <<= 1;
    int nq = m2 >> 10;
    for (int q = 0; q < nq; q++) { int s2 = t + (q << 10); if (s2 >= n) keys[s2] = ~0ull; }
    __syncthreads();

    unsigned long long myKey;
    if (m2 == 2048) {
        // ---- fast 2048-element bitonic: 2 elems/thread, shfl for j<=32 ----
        const int i0 = t, i1 = t + 1024;
        unsigned long long e0 = keys[i0], e1 = keys[i1];
        #pragma unroll
        for (int k = 2; k <= 64; k <<= 1) {          // 21 passes, zero barriers
            #pragma unroll
            for (int j = k >> 1; j > 0; j >>= 1) {
                unsigned long long p0 = __shfl_xor(e0, j);
                unsigned long long p1 = __shfl_xor(e1, j);
                bool sel0 = ((i0 & k) == 0) != ((i0 & j) != 0);
                bool sel1 = ((i1 & k) == 0) != ((i1 & j) != 0);
                e0 = sel0 ? (e0 < p0 ? e0 : p0) : (e0 > p0 ? e0 : p0);
                e1 = sel1 ? (e1 < p1 ? e1 : p1) : (e1 > p1 ? e1 : p1);
            }
        }
        for (int k = 128; k <= 2048; k <<= 1) {
            keys[i0] = e0; keys[i1] = e1;
            __syncthreads();
            for (int j = k >> 1; j >= 64; j >>= 1) { // LDS passes (j crosses waves)
                #pragma unroll
                for (int q = 0; q < 2; q++) {
                    int i = t + (q << 10);
                    int ixj = i ^ j;
                    if (ixj > i) {
                        unsigned long long a = keys[i], bb2 = keys[ixj];
                        bool up = ((i & k) == 0);
                        if ((a > bb2) == up) { keys[i] = bb2; keys[ixj] = a; }
                    }
                }
                __syncthreads();
            }
            e0 = keys[i0]; e1 = keys[i1];
            #pragma unroll
            for (int j = 32; j > 0; j >>= 1) {       // in-wave tail, zero barriers
                unsigned long long p0 = __shfl_xor(e0, j);
                unsigned long long p1 = __shfl_xor(e1, j);
                bool sel0 = ((i0 & k) == 0) != ((i0 & j) != 0);
                bool sel1 = ((i1 & k) == 0) != ((i1 & j) != 0);
                e0 = sel0 ? (e0 < p0 ? e0 : p0) : (e0 > p0 ? e0 : p0);
                e1 = sel1 ? (e1 < p1 ? e1 : p1) : (e1 > p1 ? e1 : p1);
            }
        }
        myKey = e0;                                  // position t = rank t, straight from reg
    } else {
        // ---- generic fallback (n > 2048; unreachable for this data, kept for correctness) ----
        for (int k = 2; k <= m2; k <<= 1) {
            for (int j = k >> 1; j > 0; j >>= 1) {
                for (int q = 0; q < nq; q++) {
                    int i = t + (q << 10);
                    int ixj = i ^ j;
                    if (ixj > i) {
                        unsigned long long a = keys[i], bb2 = keys[ixj];
                        bool up = ((i & k) == 0);
                        if ((a > bb2) == up) { keys[i] = bb2; keys[ixj] = a; }
                    }
                }
                __syncthreads();
            }
        }
        myKey = keys[t];
    }

    // ---- decode rank t ----
    int o = (b << 10) + t;
    if (t < n) {
        unsigned kk = (unsigned)(myKey >> 32);
        unsigned mm = ~kk;
        unsigned bits = (mm & 0x80000000u) ? (mm & 0x7FFFFFFFu) : ~mm;
        topconf[o] = __uint_as_float(bits);     // exact original score
        topidx[o] = (unsigned)(myKey & 0xFFFFFFFFu);
    } else {
        topconf[o] = -1.0f;
        topidx[o] = IDX_PAD;
    }
}

// ---------------- kernel 3: exact argmax + box build for the 16K survivors only ----------------
__global__ __launch_bounds__(256) void argmax_gather(const float* __restrict__ x,
                                                     const unsigned* __restrict__ topidx,
                                                     float4* __restrict__ topbox,
                                                     float4* __restrict__ topoff,
                                                     float* __restrict__ topcls) {
#pragma clang fp contract(off)
    int gid = blockIdx.x * 256 + threadIdx.x;
    int o = gid >> 2;                           // entry in [0, BATCH*KPRE)
    int q = gid & 3;
    int b = o >> 10;
    unsigned idx = topidx[o];

    float4 box = make_float4(0.f, 0.f, 0.f, 0.f);
    float clsf = 0.f;
    if (idx != IDX_PAD) {
        size_t base = ((size_t)b * NBOX + idx) * NCH;
        float obj = x[base + 4];
        int cbase = 5 + q * 20;
        float v = -1e30f; int c = 0;
        #pragma unroll
        for (int j = 0; j < 20; j++) {
            float s = x[base + cbase + j] * obj;
            if (s > v) { v = s; c = q * 20 + j; }      // strict > = first occurrence
        }
        #pragma unroll
        for (int off = 1; off <= 2; off <<= 1) {
            float ov = __shfl_xor(v, off);
            int   oc = __shfl_xor(c, off);
            if (ov > v || (ov == v && oc < c)) { v = ov; c = oc; }
        }
        if (q == 0) {
            float cx = x[base + 0], cy = x[base + 1], w = x[base + 2], h = x[base + 3];
            box = make_float4(cx - w * 0.5f, cy - h * 0.5f, cx + w * 0.5f, cy + h * 0.5f);
            clsf = (float)c;
        }
    }
    if (q == 0) {
        topbox[o] = box;
        topcls[o] = clsf;
        float off = clsf * 4096.0f;
        topoff[o] = make_float4(box.x + off, box.y + off, box.z + off, box.w + off);
    }
}

// ---------------- kernel 4: pairwise IoU bitmask, TRANSPOSED LDS (conflict-free) ----------------
__global__ __launch_bounds__(256) void iou_mask(const float4* __restrict__ topoff,
                                                unsigned long long* __restrict__ mask,
                                                unsigned short* __restrict__ summ) {
#pragma clang fp contract(off)
    __shared__ float4 soff[KPRE];
    int b = blockIdx.x >> 6;
    int blk = blockIdx.x & 63;
    int t = threadIdx.x;
    // contiguous LDS slots (no write conflict); permuted global read still 16 lines/instr
    for (int q = 0; q < 4; q++) {
        int u = t + q * 256;                       // LDS slot
        int s = ((u & 15) << 6) | (u >> 4);        // source box = invperm(u)
        soff[u] = topoff[(b << 10) + s];
    }
    __syncthreads();
    int i = (blk << 4) + (t >> 4);
    int w = t & 15;
    unsigned long long bits = 0;
    int jbase = w << 6;
    if (jbase + 63 > i) {                          // lower-triangle words are identically 0
        float4 a = soff[((i & 63) << 4) | (i >> 6)];
        float area_a = (a.z - a.x) * (a.w - a.y);
        for (int jj = 0; jj < 64; jj++) {
            int j = jbase + jj;
            float4 bb = soff[(jj << 4) | w];       // transposed slot for box j
            float area_b = (bb.z - bb.x) * (bb.w - bb.y);
            float ltx = fmaxf(a.x, bb.x), lty = fmaxf(a.y, bb.y);
            float rbx = fminf(a.z, bb.z), rby = fminf(a.w, bb.w);
            float wx = fmaxf(rbx - ltx, 0.0f), wy = fmaxf(rby - lty, 0.0f);
            float inter = wx * wy;
            float iou = inter / (area_a + area_b - inter + 1e-7f);
            if (j > i && iou > 0.45f) bits |= (1ull << jj);
        }
    }
    mask[((size_t)((b << 10) + i) << 4) + w] = bits;
    unsigned long long bal = __ballot(bits != 0ull);
    if (w == 0) {
        int l = t & 63;
        summ[(b << 10) + i] = (unsigned short)((bal >> ((l >> 4) << 4)) & 0xFFFFull);
    }
}

// ---------------- kernel 5: greedy suppression + ordered output (1 block / batch) ----------------
__global__ __launch_bounds__(1024) void nms_finalize(const unsigned long long* __restrict__ mask,
                                                     const unsigned short* __restrict__ summ,
                                                     const float* __restrict__ topconf,
                                                     const float4* __restrict__ topbox,
                                                     const float* __restrict__ topcls,
                                                     float* __restrict__ dets,
                                                     float* __restrict__ vmask) {
    __shared__ unsigned long long kb[16];
    int b = blockIdx.x, tid = threadIdx.x;

    if (tid < 64) {
        int lane = tid;
        const unsigned long long* mrow = mask + ((size_t)b << 14);
        unsigned long long keep0[16];
        #pragma unroll
        for (int c = 0; c < 16; c++) {
            float cf = topconf[(b << 10) + (c << 6) + lane];
            keep0[c] = __ballot(cf > 0.0f);
        }
        unsigned nz[16];
        #pragma unroll
        for (int t = 0; t < 16; t++)
            nz[t] = (unsigned)summ[(b << 10) + (t << 6) + lane];
        unsigned long long diag[16];
        #pragma unroll
        for (int t = 0; t < 16; t++)
            diag[t] = mrow[((size_t)((t << 6) + lane) << 4) + t];

        unsigned long long remv[16];
        #pragma unroll
        for (int t = 0; t < 16; t++) remv[t] = 0;

        #pragma unroll
        for (int t = 0; t < 16; t++) {
            unsigned long long live = keep0[t] & ~remv[t];
            unsigned long long kept = live;
            unsigned long long pend = live & __ballot((nz[t] >> t) & 1u);
            while (pend) {
                int j = (int)__ffsll(pend) - 1;
                pend &= pend - 1;
                if ((kept >> j) & 1ull) {
                    unsigned long long dj = __shfl(diag[t], j);
                    kept &= ~dj;
                    pend &= ~dj;
                }
            }
            if (lane == 0) kb[t] = kept;

            #pragma unroll
            for (int w = 0; w < 16; w++) {
                if (w > t) {
                    unsigned long long wm = kept & __ballot((nz[t] >> w) & 1u);
                    while (wm) {
                        int j = (int)__ffsll(wm) - 1;
                        wm &= wm - 1;
                        remv[w] |= mrow[((size_t)((t << 6) + j) << 4) + w];
                    }
                }
            }
        }
    }
    __syncthreads();

    int r = tid;
    int w = r >> 6, l = r & 63;
    unsigned long long word = kb[w];
    int keep = (int)((word >> l) & 1ull);
    int base = 0, total = 0;
    #pragma unroll
    for (int q = 0; q < 16; q++) {
        int c = __popcll(kb[q]);
        total += c;
        if (q < w) base += c;
    }
    int rank = base + __popcll((l == 0) ? 0ull : (word & ((~0ull) >> (64 - l))));
    float* drow = dets + (size_t)b * (MAXDET * 6);
    float* vm = vmask + (size_t)b * MAXDET;
    if (r < MAXDET && r >= total) {
#pragma unroll
        for (int cc = 0; cc < 6; cc++) drow[r * 6 + cc] = 0.0f;
        vm[r] = 0.0f;
    }
    if (keep && rank < MAXDET) {
        int o = (b << 10) + r;
        float4 bx = topbox[o];
        drow[rank * 6 + 0] = bx.x;
        drow[rank * 6 + 1] = bx.y;
        drow[rank * 6 + 2] = bx.z;
        drow[rank * 6 + 3] = bx.w;
        drow[rank * 6 + 4] = topconf[o];
        drow[rank * 6 + 5] = topcls[o];
        vm[rank] = 1.0f;
    }
}

// ---------------- launcher ----------------
extern "C" void kernel_launch(void* const* d_in, const int* in_sizes, int n_in,
                              void* d_out, int out_size, void* d_ws, size_t ws_size,
                              hipStream_t stream) {
    const float* x = (const float*)d_in[0];
    char* w = (char*)d_ws;

    // workspace layout (bytes), total 4,463,616
    unsigned long long* mask    = (unsigned long long*)(w + 0);        // 2,097,152
    unsigned*           k32     = (unsigned*)(w + 2097152);            // 1,612,800
    float4*             topbox  = (float4*)(w + 3709952);              // 262,144
    float4*             topoff  = (float4*)(w + 3972096);              // 262,144
    float*              topconf = (float*)(w + 4234240);               // 65,536
    float*              topcls  = (float*)(w + 4299776);               // 65,536
    unsigned*           topidx  = (unsigned*)(w + 4365312);            // 65,536
    unsigned short*     summ    = (unsigned short*)(w + 4430848);      // 32,768
    if (ws_size < 4463616) return;  // insufficient scratch -> deterministic failure

    score_kernel<<<(BATCH * NBOX * 4) / 256, 256, 0, stream>>>(x, k32);
    sort_gather<<<BATCH, 1024, 0, stream>>>(k32, topconf, topidx);
    argmax_gather<<<(BATCH * KPRE * 4) / 256, 256, 0, stream>>>(x, topidx, topbox, topoff, topcls);
    iou_mask<<<BATCH * 64, 256, 0, stream>>>(topoff, mask, summ);

    float* dets = (float*)d_out;
    float* vmask = dets + (size_t)BATCH * MAXDET * 6;
    nms_finalize<<<BATCH, 1024, 0, stream>>>(mask, summ, topconf, topbox, topcls, dets, vmask);
}